// Round 9
// baseline (123.435 us; speedup 1.0000x reference)
//
#include <hip/hip_runtime.h>
#include <hip/hip_bf16.h>

#define D 128
#define NPB 16           // nodes per block in fallback logit kernel
#define CHUNK 8192       // edges per bin block
#define BKN 64           // dst nodes per bucket
#define MAXBUCK 1024     // max buckets
#define NCHUNK_MAX 128   // max bin chunks supported by merge
#define CAP 4096         // per-bucket LDS edge buffer (avg ~1024, 4x headroom)

typedef __attribute__((ext_vector_type(8))) short bf16x8;
typedef __attribute__((ext_vector_type(4))) float f32x4;

__device__ __forceinline__ unsigned short f2bf_rne(float f) {
  unsigned u = __float_as_uint(f);
  unsigned r = (u + 0x7FFFu + ((u >> 16) & 1u)) >> 16;
  return (unsigned short)r;
}

__device__ __forceinline__ float fast_tanh(float x) {
  float e = __expf(2.0f * x);
  return 1.0f - 2.0f / (e + 1.0f);
}

// split 8 consecutive f32 into bf16 hi/lo fragments (in registers)
__device__ __forceinline__ void split8(const float* __restrict__ p,
                                       bf16x8& hv, bf16x8& lv) {
  float4 a = *(const float4*)p;
  float4 b = *(const float4*)(p + 4);
  float xs[8] = {a.x, a.y, a.z, a.w, b.x, b.y, b.z, b.w};
#pragma unroll
  for (int i = 0; i < 8; ++i) {
    unsigned short h = f2bf_rne(xs[i]);
    float hf = __uint_as_float((unsigned)h << 16);
    hv[i] = (short)h;
    lv[i] = (short)f2bf_rne(xs[i] - hf);
  }
}

// ---------------------------------------------------------------------------
// logit chain fused (R8-verified): in-register W1 split, split-bf16 MFMA,
// nbf export, cross-wave LDS reduction, exp -> explog.
// ---------------------------------------------------------------------------
__global__ __launch_bounds__(256, 2) void logit_mfma_kernel(
    const float* __restrict__ Nm, const float* __restrict__ W1,
    const float* __restrict__ w2, float* __restrict__ explog,
    unsigned short* __restrict__ nbf, int n_nodes) {
  __shared__ unsigned short lhi[64 * 128];
  __shared__ unsigned short llo[64 * 128];
  __shared__ float part[4][64];
  const int tid = threadIdx.x;
  const int w = tid >> 6;
  const int l = tid & 63;
  const int lg = l >> 4;
  const int ln = l & 15;
  const int base = blockIdx.x * 64;

  bf16x8 Bh[2][4], Bl[2][4];
#pragma unroll
  for (int ntl = 0; ntl < 2; ++ntl) {
    int n = (w * 2 + ntl) * 16 + ln;
#pragma unroll
    for (int kt = 0; kt < 4; ++kt) {
      int k = kt * 32 + lg * 8;
      split8(W1 + n * 128 + k, Bh[ntl][kt], Bl[ntl][kt]);
    }
  }

#pragma unroll
  for (int i = 0; i < 8; ++i) {
    int flat = tid + i * 256;
    int row = flat >> 5;
    int c4 = flat & 31;
    int grow = base + row;
    if (grow >= n_nodes) grow = n_nodes - 1;
    float4 v = *(const float4*)(Nm + (size_t)grow * D + c4 * 4);
    unsigned short h0 = f2bf_rne(v.x), h1 = f2bf_rne(v.y);
    unsigned short h2 = f2bf_rne(v.z), h3 = f2bf_rne(v.w);
    unsigned short o0 = f2bf_rne(v.x - __uint_as_float((unsigned)h0 << 16));
    unsigned short o1 = f2bf_rne(v.y - __uint_as_float((unsigned)h1 << 16));
    unsigned short o2 = f2bf_rne(v.z - __uint_as_float((unsigned)h2 << 16));
    unsigned short o3 = f2bf_rne(v.w - __uint_as_float((unsigned)h3 << 16));
    int boff = (c4 * 8) ^ ((row & 7) << 4);
    *(ushort4*)((char*)lhi + row * 256 + boff) = make_ushort4(h0, h1, h2, h3);
    *(ushort4*)((char*)llo + row * 256 + boff) = make_ushort4(o0, o1, o2, o3);
    *(ushort4*)(nbf + (size_t)grow * D + c4 * 4) =
        make_ushort4(h0, h1, h2, h3);
  }
  __syncthreads();

  f32x4 acc[4][2];
#pragma unroll
  for (int mt = 0; mt < 4; ++mt)
#pragma unroll
    for (int ntl = 0; ntl < 2; ++ntl) acc[mt][ntl] = (f32x4){0.f, 0.f, 0.f, 0.f};

#pragma unroll
  for (int mt = 0; mt < 4; ++mt) {
    int row = mt * 16 + ln;
    bf16x8 Ah[4], Al[4];
#pragma unroll
    for (int kt = 0; kt < 4; ++kt) {
      int boff = (kt * 64 + lg * 16) ^ ((row & 7) << 4);
      Ah[kt] = *(const bf16x8*)((const char*)lhi + row * 256 + boff);
      Al[kt] = *(const bf16x8*)((const char*)llo + row * 256 + boff);
    }
#pragma unroll
    for (int ntl = 0; ntl < 2; ++ntl) {
#pragma unroll
      for (int kt = 0; kt < 4; ++kt) {
        acc[mt][ntl] = __builtin_amdgcn_mfma_f32_16x16x32_bf16(
            Ah[kt], Bh[ntl][kt], acc[mt][ntl], 0, 0, 0);
        acc[mt][ntl] = __builtin_amdgcn_mfma_f32_16x16x32_bf16(
            Ah[kt], Bl[ntl][kt], acc[mt][ntl], 0, 0, 0);
        acc[mt][ntl] = __builtin_amdgcn_mfma_f32_16x16x32_bf16(
            Al[kt], Bh[ntl][kt], acc[mt][ntl], 0, 0, 0);
      }
    }
  }

  float w2a = w2[(w * 2 + 0) * 16 + ln];
  float w2b = w2[(w * 2 + 1) * 16 + ln];
#pragma unroll
  for (int mt = 0; mt < 4; ++mt) {
    float s0 = fast_tanh(acc[mt][0][0]) * w2a + fast_tanh(acc[mt][1][0]) * w2b;
    float s1 = fast_tanh(acc[mt][0][1]) * w2a + fast_tanh(acc[mt][1][1]) * w2b;
    float s2 = fast_tanh(acc[mt][0][2]) * w2a + fast_tanh(acc[mt][1][2]) * w2b;
    float s3 = fast_tanh(acc[mt][0][3]) * w2a + fast_tanh(acc[mt][1][3]) * w2b;
#pragma unroll
    for (int mask = 1; mask < 16; mask <<= 1) {
      s0 += __shfl_xor(s0, mask);
      s1 += __shfl_xor(s1, mask);
      s2 += __shfl_xor(s2, mask);
      s3 += __shfl_xor(s3, mask);
    }
    if (ln < 4) {
      float sv = (ln == 0) ? s0 : (ln == 1) ? s1 : (ln == 2) ? s2 : s3;
      part[w][mt * 16 + lg * 4 + ln] = sv;
    }
  }
  __syncthreads();
  if (tid < 64) {
    int node = base + tid;
    if (node < n_nodes) {
      float t = part[0][tid] + part[1][tid] + part[2][tid] + part[3][tid];
      explog[node] = expf(t);
    }
  }
}

// ---------------------------------------------------------------------------
// Bin (R6-verified): chunk-local LDS counting sort by bucket (dst>>6);
// coalesced output. binout entry = src | (dst&63)<<16; dir = run starts.
// ---------------------------------------------------------------------------
__global__ __launch_bounds__(256) void bin_kernel(
    const int* __restrict__ src, const int* __restrict__ dst,
    unsigned* __restrict__ binout, unsigned short* __restrict__ dir,
    int n_edges, int nbuck) {
  __shared__ unsigned cnt[MAXBUCK];
  __shared__ unsigned cur[MAXBUCK];
  __shared__ unsigned ebuf[CHUNK];
  __shared__ int sdata[256];
  const int tid = threadIdx.x;
  const int blk = blockIdx.x;
  const int ebase = blk * CHUNK;
  const int chunkN = min(CHUNK, n_edges - ebase);

  for (int i = tid; i < MAXBUCK; i += 256) cnt[i] = 0;
  __syncthreads();

  for (int i = tid; i < chunkN; i += 256) {
    int d = dst[ebase + i];
    atomicAdd(&cnt[d >> 6], 1u);
  }
  __syncthreads();

  int t4 = tid * 4;
  int c0 = cnt[t4], c1 = cnt[t4 + 1], c2 = cnt[t4 + 2], c3 = cnt[t4 + 3];
  int s = c0 + c1 + c2 + c3;
  sdata[tid] = s;
  __syncthreads();
  for (int d = 1; d < 256; d <<= 1) {
    int v = (tid >= d) ? sdata[tid - d] : 0;
    __syncthreads();
    sdata[tid] += v;
    __syncthreads();
  }
  int tb = sdata[tid] - s;
  cur[t4] = tb;
  cur[t4 + 1] = tb + c0;
  cur[t4 + 2] = tb + c0 + c1;
  cur[t4 + 3] = tb + c0 + c1 + c2;
  __syncthreads();

  size_t dbase = (size_t)blk * (nbuck + 1);
  for (int k = tid; k < nbuck; k += 256) dir[dbase + k] = (unsigned short)cur[k];
  if (tid == 0) dir[dbase + nbuck] = (unsigned short)chunkN;
  __syncthreads();

  for (int i = tid; i < chunkN; i += 256) {
    int d = dst[ebase + i];
    int sv = src[ebase + i];
    unsigned slot = atomicAdd(&cur[d >> 6], 1u);
    ebuf[slot] = (unsigned)sv | ((unsigned)(d & 63) << 16);
  }
  __syncthreads();

  for (int i = tid; i < chunkN; i += 256) binout[ebase + i] = ebuf[i];
}

// ---------------------------------------------------------------------------
// Fused merge+accum: one block per 64-node bucket.
//  1) gather bucket runs from bin chunks into LDS (raw order)
//  2) 64-counter counting sort into (ebuf2, xbuf) with x=explog[src] gathered
//  3) each wave register-accumulates 16 nodes from LDS, one nbf gather/edge,
//     writes its output rows once (no global sorted array, no offsets).
// ---------------------------------------------------------------------------
__global__ __launch_bounds__(256) void merge_accum_kernel(
    const unsigned* __restrict__ binout, const unsigned short* __restrict__ dir,
    const float* __restrict__ explog, const unsigned* __restrict__ nbf32,
    float* __restrict__ out, int n_nodes, int nbuck, int nblk_bin) {
  __shared__ unsigned ebuf[CAP];   // raw gathered edges
  __shared__ unsigned ebuf2[CAP];  // dst-sorted edges
  __shared__ float xbuf[CAP];      // exp(logit[src]) per sorted edge
  __shared__ int lens[NCHUNK_MAX], cstart[NCHUNK_MAX], ls0[NCHUNK_MAX];
  __shared__ int cnt[BKN], nstart[BKN], cur[BKN];
  __shared__ int total;
  const int tid = threadIdx.x;
  const int w = tid >> 6, lane = tid & 63;
  const int bk = blockIdx.x;
  const int node0 = bk * BKN;

  if (tid < nblk_bin) {
    size_t dbase = (size_t)tid * (nbuck + 1);
    int s0 = dir[dbase + bk];
    int s1 = dir[dbase + bk + 1];
    ls0[tid] = s0;
    lens[tid] = s1 - s0;
  }
  if (tid < BKN) cnt[tid] = 0;
  __syncthreads();
  if (tid == 0) {
    int run = 0;
    for (int r = 0; r < nblk_bin; ++r) {
      cstart[r] = run;
      run += lens[r];
    }
    total = (run > CAP) ? CAP : run;
  }
  __syncthreads();
  const int tot = total;

  // 1) gather runs
  for (int r = w; r < nblk_bin; r += 4) {
    int len = lens[r], cs = cstart[r];
    if (cs >= CAP) continue;
    if (cs + len > CAP) len = CAP - cs;
    const unsigned* g = binout + (size_t)r * CHUNK + ls0[r];
    for (int i = lane; i < len; i += 64) ebuf[cs + i] = g[i];
  }
  __syncthreads();

  // 2) count + scan + scatter (with explog gather)
  for (int i = tid; i < tot; i += 256) atomicAdd(&cnt[ebuf[i] >> 16], 1);
  __syncthreads();
  if (tid == 0) {
    int run = 0;
    for (int t = 0; t < BKN; ++t) {
      nstart[t] = run;
      run += cnt[t];
    }
  }
  __syncthreads();
  if (tid < BKN) cur[tid] = nstart[tid];
  __syncthreads();
  for (int i = tid; i < tot; i += 256) {
    unsigned p = ebuf[i];
    int pos = atomicAdd(&cur[p >> 16], 1);
    ebuf2[pos] = p;
    xbuf[pos] = explog[p & 0xFFFF];
  }
  __syncthreads();

  // 3) per-wave register accumulation: wave w owns nodes [w*16, w*16+16)
  for (int t = w * 16; t < w * 16 + 16; ++t) {
    int node = node0 + t;
    if (node >= n_nodes) break;
    int beg = nstart[t];
    int end = beg + cnt[t];
    float acc0 = 0.f, acc1 = 0.f, den = 0.f;
    if (end > beg) {
      int last = end - 1;
      for (int e = beg; e < end; e += 8) {
        unsigned p[8];
        float x[8];
        unsigned u[8];
#pragma unroll
        for (int i = 0; i < 8; ++i) {
          int ei = e + i;
          int ec = (ei < last) ? ei : last;
          p[i] = ebuf2[ec];
          x[i] = xbuf[ec];
        }
#pragma unroll
        for (int i = 0; i < 8; ++i) {
          int si = p[i] & 0xFFFF;
          u[i] = nbf32[(size_t)si * 64 + lane];
        }
#pragma unroll
        for (int i = 0; i < 8; ++i) {
          float xi = (e + i < end) ? x[i] : 0.f;
          den += xi;
          acc0 += xi * __uint_as_float(u[i] << 16);
          acc1 += xi * __uint_as_float(u[i] & 0xFFFF0000u);
        }
      }
    }
    float inv = (end > beg) ? 1.0f / den : 0.f;
    *(float2*)(out + (size_t)node * D + lane * 2) =
        make_float2(acc0 * inv, acc1 * inv);
  }
}

// ---------------------------------------------------------------------------
// Fallback path: scalar logit + per-edge atomics (R1, verified)
// ---------------------------------------------------------------------------
__global__ __launch_bounds__(256) void logit_kernel(
    const float* __restrict__ Nm, const float* __restrict__ W1,
    const float* __restrict__ w2, float* __restrict__ logit, int n_nodes) {
  __shared__ float w1t[32 * 129];
  const int tid = threadIdx.x;
  const int j = tid & 127;
  const int half = tid >> 7;
  const int base = blockIdx.x * NPB;
  float acc[8];
#pragma unroll
  for (int g = 0; g < 8; ++g) acc[g] = 0.f;
  for (int c = 0; c < 4; ++c) {
    __syncthreads();
    for (int idx = tid; idx < 128 * 32; idx += 256) {
      int kl = idx & 31, jj = idx >> 5;
      w1t[kl * 129 + jj] = W1[jj * 128 + c * 32 + kl];
    }
    __syncthreads();
#pragma unroll
    for (int g = 0; g < 8; ++g) {
      int node = base + g * 2 + half;
      if (node < n_nodes) {
        const float4* nrow =
            reinterpret_cast<const float4*>(Nm + (size_t)node * D + c * 32);
        float a = acc[g];
#pragma unroll
        for (int k4 = 0; k4 < 8; ++k4) {
          float4 nv = nrow[k4];
          int kl = k4 * 4;
          a += nv.x * w1t[(kl + 0) * 129 + j];
          a += nv.y * w1t[(kl + 1) * 129 + j];
          a += nv.z * w1t[(kl + 2) * 129 + j];
          a += nv.w * w1t[(kl + 3) * 129 + j];
        }
        acc[g] = a;
      }
    }
  }
  const float w2j = w2[j];
#pragma unroll
  for (int g = 0; g < 8; ++g) {
    int node = base + g * 2 + half;
    float t = tanhf(acc[g]) * w2j;
#pragma unroll
    for (int off = 32; off; off >>= 1) t += __shfl_down(t, off);
    if ((tid & 63) == 0 && node < n_nodes) atomicAdd(&logit[node], t);
  }
}

__global__ __launch_bounds__(256) void denom_kernel(
    const int* __restrict__ src, const int* __restrict__ dst,
    const float* __restrict__ logit, float* __restrict__ denom, int n_edges) {
  int e = blockIdx.x * 256 + threadIdx.x;
  if (e < n_edges) {
    float ex = expf(logit[src[e]]);
    atomicAdd(&denom[dst[e]], ex);
  }
}

__global__ __launch_bounds__(256) void scatter_kernel(
    const int* __restrict__ src, const int* __restrict__ dst,
    const float* __restrict__ logit, const float* __restrict__ denom,
    const float* __restrict__ Nm, float* __restrict__ out, int n_edges) {
  int wave = (blockIdx.x * 256 + threadIdx.x) >> 6;
  int lane = threadIdx.x & 63;
  if (wave >= n_edges) return;
  int s = src[wave];
  int d = dst[wave];
  float a = expf(logit[s]) / denom[d];
  float v0 = Nm[(size_t)s * D + lane];
  float v1 = Nm[(size_t)s * D + 64 + lane];
  atomicAdd(&out[(size_t)d * D + lane], a * v0);
  atomicAdd(&out[(size_t)d * D + 64 + lane], a * v1);
}

static inline char* align_up(char* p, size_t a) {
  return (char*)(((uintptr_t)p + a - 1) & ~(uintptr_t)(a - 1));
}

extern "C" void kernel_launch(void* const* d_in, const int* in_sizes, int n_in,
                              void* d_out, int out_size, void* d_ws,
                              size_t ws_size, hipStream_t stream) {
  const float* Nm  = (const float*)d_in[0];
  const float* W1  = (const float*)d_in[1];
  const float* w2  = (const float*)d_in[2];
  const int*   src = (const int*)d_in[3];
  const int*   dst = (const int*)d_in[4];
  float* out = (float*)d_out;

  const int n_nodes = in_sizes[0] / D;
  const int n_edges = in_sizes[3];
  const int n_pad = (n_nodes + 63) & ~63;
  const int nbuck = (n_nodes + BKN - 1) / BKN;
  const int nblk_bin = (n_edges + CHUNK - 1) / CHUNK;

  // carve workspace
  char* p = (char*)d_ws;
  float* explog = (float*)p;     p = align_up(p + (size_t)n_pad * 4, 256);
  float* denomF = (float*)p;     p = align_up(p + (size_t)n_pad * 4, 256);
  unsigned short* nbf = (unsigned short*)p;
  p = align_up(p + (size_t)n_nodes * D * 2, 256);
  unsigned* binout = (unsigned*)p;
  p = align_up(p + (size_t)nblk_bin * CHUNK * 4, 256);
  unsigned short* dir = (unsigned short*)p;
  p = align_up(p + (size_t)nblk_bin * (nbuck + 1) * 2, 256);
  size_t needed = (size_t)(p - (char*)d_ws);

  const bool fits = (ws_size >= needed) && (n_nodes <= 65535) &&
                    (nbuck <= MAXBUCK) && (nblk_bin <= NCHUNK_MAX) &&
                    ((n_edges / (nbuck > 0 ? nbuck : 1)) * 3 < CAP);

  if (fits) {
    // logit chain (fused: W1 split + logits + exp + nbf export)
    int nblk1 = (n_nodes + 63) / 64;
    logit_mfma_kernel<<<nblk1, 256, 0, stream>>>(Nm, W1, w2, explog, nbf,
                                                 n_nodes);

    // edge sort stage 1: chunk-local bin
    bin_kernel<<<nblk_bin, 256, 0, stream>>>(src, dst, binout, dir, n_edges,
                                             nbuck);

    // fused sort stage 2 + accumulation
    merge_accum_kernel<<<nbuck, 256, 0, stream>>>(
        binout, dir, explog, (const unsigned*)nbf, out, n_nodes, nbuck,
        nblk_bin);
  } else {
    // fallback: scalar logit + R1 atomic path
    float* logit = explog;
    float* denom = denomF;
    hipMemsetAsync(logit, 0, (size_t)n_pad * sizeof(float), stream);
    hipMemsetAsync(denom, 0, (size_t)n_pad * sizeof(float), stream);
    hipMemsetAsync(out, 0, (size_t)out_size * sizeof(float), stream);
    int nblk1 = (n_nodes + NPB - 1) / NPB;
    logit_kernel<<<nblk1, 256, 0, stream>>>(Nm, W1, w2, logit, n_nodes);
    int eblk = (n_edges + 255) / 256;
    denom_kernel<<<eblk, 256, 0, stream>>>(src, dst, logit, denom, n_edges);
    int nblk3 = (n_edges + 3) / 4;
    scatter_kernel<<<nblk3, 256, 0, stream>>>(src, dst, logit, denom, Nm, out,
                                              n_edges);
  }
}

// Round 10
// 89.002 us; speedup vs baseline: 1.3869x; 1.3869x over previous
//
#include <hip/hip_runtime.h>
#include <hip/hip_bf16.h>

#define D 128
#define NPB 16           // nodes per block in fallback logit kernel
#define CHUNK 8192       // edges per bin block
#define BKN 64           // dst nodes per bucket
#define MAXBUCK 1024     // max buckets
#define NCHUNK_MAX 128   // max bin chunks supported by merge
#define CAP 4096         // per-bucket window & merge LDS buffer (avg ~1024)

typedef __attribute__((ext_vector_type(8))) short bf16x8;
typedef __attribute__((ext_vector_type(4))) float f32x4;

__device__ __forceinline__ unsigned short f2bf_rne(float f) {
  unsigned u = __float_as_uint(f);
  unsigned r = (u + 0x7FFFu + ((u >> 16) & 1u)) >> 16;
  return (unsigned short)r;
}

__device__ __forceinline__ float fast_tanh(float x) {
  float e = __expf(2.0f * x);
  return 1.0f - 2.0f / (e + 1.0f);
}

__device__ __forceinline__ void split8(const float* __restrict__ p,
                                       bf16x8& hv, bf16x8& lv) {
  float4 a = *(const float4*)p;
  float4 b = *(const float4*)(p + 4);
  float xs[8] = {a.x, a.y, a.z, a.w, b.x, b.y, b.z, b.w};
#pragma unroll
  for (int i = 0; i < 8; ++i) {
    unsigned short h = f2bf_rne(xs[i]);
    float hf = __uint_as_float((unsigned)h << 16);
    hv[i] = (short)h;
    lv[i] = (short)f2bf_rne(xs[i] - hf);
  }
}

struct SMLogit {
  unsigned short lhi[64 * 128];
  unsigned short llo[64 * 128];
  float part[4][64];
};
struct SMBin {
  unsigned cnt[MAXBUCK];
  unsigned cur[MAXBUCK];
  unsigned ebuf[CHUNK];
  int sdata[256];
};
union SMU {
  SMLogit lg;
  SMBin bn;
};

// ---------------------------------------------------------------------------
// Combined kernel: blocks [0, nblk1) run the logit chain (W1 split + MFMA +
// nbf export + exp), blocks [nblk1, nblk1+nblk_bin) run the bin counting
// sort. Independent work co-scheduled in one launch: bin's memory-bound
// blocks overlap logit's compute-bound blocks.
// ---------------------------------------------------------------------------
__global__ __launch_bounds__(256, 2) void logit_bin_kernel(
    const float* __restrict__ Nm, const float* __restrict__ W1,
    const float* __restrict__ w2, float* __restrict__ explog,
    unsigned short* __restrict__ nbf, int n_nodes,
    const int* __restrict__ src, const int* __restrict__ dst,
    unsigned* __restrict__ binout, unsigned short* __restrict__ dir,
    int n_edges, int nbuck, int nblk1) {
  __shared__ SMU sm;
  const int tid = threadIdx.x;

  if ((int)blockIdx.x < nblk1) {
    // ================= logit role (R8-verified) =================
    const int w = tid >> 6;
    const int l = tid & 63;
    const int lg = l >> 4;
    const int ln = l & 15;
    const int base = blockIdx.x * 64;

    bf16x8 Bh[2][4], Bl[2][4];
#pragma unroll
    for (int ntl = 0; ntl < 2; ++ntl) {
      int n = (w * 2 + ntl) * 16 + ln;
#pragma unroll
      for (int kt = 0; kt < 4; ++kt) {
        int k = kt * 32 + lg * 8;
        split8(W1 + n * 128 + k, Bh[ntl][kt], Bl[ntl][kt]);
      }
    }

#pragma unroll
    for (int i = 0; i < 8; ++i) {
      int flat = tid + i * 256;
      int row = flat >> 5;
      int c4 = flat & 31;
      int grow = base + row;
      if (grow >= n_nodes) grow = n_nodes - 1;
      float4 v = *(const float4*)(Nm + (size_t)grow * D + c4 * 4);
      unsigned short h0 = f2bf_rne(v.x), h1 = f2bf_rne(v.y);
      unsigned short h2 = f2bf_rne(v.z), h3 = f2bf_rne(v.w);
      unsigned short o0 = f2bf_rne(v.x - __uint_as_float((unsigned)h0 << 16));
      unsigned short o1 = f2bf_rne(v.y - __uint_as_float((unsigned)h1 << 16));
      unsigned short o2 = f2bf_rne(v.z - __uint_as_float((unsigned)h2 << 16));
      unsigned short o3 = f2bf_rne(v.w - __uint_as_float((unsigned)h3 << 16));
      int boff = (c4 * 8) ^ ((row & 7) << 4);
      *(ushort4*)((char*)sm.lg.lhi + row * 256 + boff) =
          make_ushort4(h0, h1, h2, h3);
      *(ushort4*)((char*)sm.lg.llo + row * 256 + boff) =
          make_ushort4(o0, o1, o2, o3);
      *(ushort4*)(nbf + (size_t)grow * D + c4 * 4) =
          make_ushort4(h0, h1, h2, h3);
    }
    __syncthreads();

    f32x4 acc[4][2];
#pragma unroll
    for (int mt = 0; mt < 4; ++mt)
#pragma unroll
      for (int ntl = 0; ntl < 2; ++ntl)
        acc[mt][ntl] = (f32x4){0.f, 0.f, 0.f, 0.f};

#pragma unroll
    for (int mt = 0; mt < 4; ++mt) {
      int row = mt * 16 + ln;
      bf16x8 Ah[4], Al[4];
#pragma unroll
      for (int kt = 0; kt < 4; ++kt) {
        int boff = (kt * 64 + lg * 16) ^ ((row & 7) << 4);
        Ah[kt] = *(const bf16x8*)((const char*)sm.lg.lhi + row * 256 + boff);
        Al[kt] = *(const bf16x8*)((const char*)sm.lg.llo + row * 256 + boff);
      }
#pragma unroll
      for (int ntl = 0; ntl < 2; ++ntl) {
#pragma unroll
        for (int kt = 0; kt < 4; ++kt) {
          acc[mt][ntl] = __builtin_amdgcn_mfma_f32_16x16x32_bf16(
              Ah[kt], Bh[ntl][kt], acc[mt][ntl], 0, 0, 0);
          acc[mt][ntl] = __builtin_amdgcn_mfma_f32_16x16x32_bf16(
              Ah[kt], Bl[ntl][kt], acc[mt][ntl], 0, 0, 0);
          acc[mt][ntl] = __builtin_amdgcn_mfma_f32_16x16x32_bf16(
              Al[kt], Bh[ntl][kt], acc[mt][ntl], 0, 0, 0);
        }
      }
    }

    float w2a = w2[(w * 2 + 0) * 16 + ln];
    float w2b = w2[(w * 2 + 1) * 16 + ln];
#pragma unroll
    for (int mt = 0; mt < 4; ++mt) {
      float s0 =
          fast_tanh(acc[mt][0][0]) * w2a + fast_tanh(acc[mt][1][0]) * w2b;
      float s1 =
          fast_tanh(acc[mt][0][1]) * w2a + fast_tanh(acc[mt][1][1]) * w2b;
      float s2 =
          fast_tanh(acc[mt][0][2]) * w2a + fast_tanh(acc[mt][1][2]) * w2b;
      float s3 =
          fast_tanh(acc[mt][0][3]) * w2a + fast_tanh(acc[mt][1][3]) * w2b;
#pragma unroll
      for (int mask = 1; mask < 16; mask <<= 1) {
        s0 += __shfl_xor(s0, mask);
        s1 += __shfl_xor(s1, mask);
        s2 += __shfl_xor(s2, mask);
        s3 += __shfl_xor(s3, mask);
      }
      if (ln < 4) {
        float sv = (ln == 0) ? s0 : (ln == 1) ? s1 : (ln == 2) ? s2 : s3;
        sm.lg.part[w][mt * 16 + lg * 4 + ln] = sv;
      }
    }
    __syncthreads();
    if (tid < 64) {
      int node = base + tid;
      if (node < n_nodes) {
        float t = sm.lg.part[0][tid] + sm.lg.part[1][tid] +
                  sm.lg.part[2][tid] + sm.lg.part[3][tid];
        explog[node] = expf(t);
      }
    }
  } else {
    // ================= bin role (R6-verified) =================
    const int blk = (int)blockIdx.x - nblk1;
    const int ebase = blk * CHUNK;
    const int chunkN = min(CHUNK, n_edges - ebase);

    for (int i = tid; i < MAXBUCK; i += 256) sm.bn.cnt[i] = 0;
    __syncthreads();

    for (int i = tid; i < chunkN; i += 256) {
      int d = dst[ebase + i];
      atomicAdd(&sm.bn.cnt[d >> 6], 1u);
    }
    __syncthreads();

    int t4 = tid * 4;
    int c0 = sm.bn.cnt[t4], c1 = sm.bn.cnt[t4 + 1];
    int c2 = sm.bn.cnt[t4 + 2], c3 = sm.bn.cnt[t4 + 3];
    int s = c0 + c1 + c2 + c3;
    sm.bn.sdata[tid] = s;
    __syncthreads();
    for (int d = 1; d < 256; d <<= 1) {
      int v = (tid >= d) ? sm.bn.sdata[tid - d] : 0;
      __syncthreads();
      sm.bn.sdata[tid] += v;
      __syncthreads();
    }
    int tb = sm.bn.sdata[tid] - s;
    sm.bn.cur[t4] = tb;
    sm.bn.cur[t4 + 1] = tb + c0;
    sm.bn.cur[t4 + 2] = tb + c0 + c1;
    sm.bn.cur[t4 + 3] = tb + c0 + c1 + c2;
    __syncthreads();

    size_t dbase = (size_t)blk * (nbuck + 1);
    for (int k = tid; k < nbuck; k += 256)
      dir[dbase + k] = (unsigned short)sm.bn.cur[k];
    if (tid == 0) dir[dbase + nbuck] = (unsigned short)chunkN;
    __syncthreads();

    for (int i = tid; i < chunkN; i += 256) {
      int d = dst[ebase + i];
      int sv = src[ebase + i];
      unsigned slot = atomicAdd(&sm.bn.cur[d >> 6], 1u);
      sm.bn.ebuf[slot] = (unsigned)sv | ((unsigned)(d & 63) << 16);
    }
    __syncthreads();

    for (int i = tid; i < chunkN; i += 256) binout[ebase + i] = sm.bn.ebuf[i];
  }
}

// ---------------------------------------------------------------------------
// Merge: one block per bucket -> private fixed window sorted[bk*CAP ...].
// Serial tid==0 scans replaced by single-wave shfl_up scans.
// ---------------------------------------------------------------------------
__global__ __launch_bounds__(256) void merge_kernel(
    const unsigned* __restrict__ binout, const unsigned short* __restrict__ dir,
    unsigned* __restrict__ sorted, int* __restrict__ offsets,
    int* __restrict__ ends, int n_nodes, int nbuck, int nblk_bin) {
  __shared__ unsigned ebuf[CAP];
  __shared__ int lens[NCHUNK_MAX], cstart[NCHUNK_MAX], ls0[NCHUNK_MAX];
  __shared__ int cnt[BKN], nstart[BKN], cur[BKN];
  __shared__ int total;
  const int tid = threadIdx.x;
  const int w = tid >> 6, lane = tid & 63;
  const int bk = blockIdx.x;
  const int node0 = bk * BKN;
  const int base = bk * CAP;

  if (tid < nblk_bin) {
    size_t dbase = (size_t)tid * (nbuck + 1);
    int s0 = dir[dbase + bk];
    int s1 = dir[dbase + bk + 1];
    ls0[tid] = s0;
    lens[tid] = s1 - s0;
  }
  if (tid < BKN) cnt[tid] = 0;
  __syncthreads();

  // chunk exclusive scan (wave 0, 2 elems/lane, shfl_up)
  if (w == 0) {
    int l0 = lane * 2, l1 = lane * 2 + 1;
    int a = (l0 < nblk_bin) ? lens[l0] : 0;
    int b = (l1 < nblk_bin) ? lens[l1] : 0;
    int sv = a + b;
    int inc = sv;
#pragma unroll
    for (int off = 1; off < 64; off <<= 1) {
      int t = __shfl_up(inc, off);
      if (lane >= off) inc += t;
    }
    int ex = inc - sv;
    if (l0 < nblk_bin) cstart[l0] = ex;
    if (l1 < nblk_bin) cstart[l1] = ex + a;
    if (lane == 63) total = (inc > CAP) ? CAP : inc;
  }
  __syncthreads();
  const int tot = total;

  // gather runs
  for (int r = w; r < nblk_bin; r += 4) {
    int len = lens[r], cs = cstart[r];
    if (cs >= CAP) continue;
    if (cs + len > CAP) len = CAP - cs;
    const unsigned* g = binout + (size_t)r * CHUNK + ls0[r];
    for (int i = lane; i < len; i += 64) ebuf[cs + i] = g[i];
  }
  __syncthreads();

  // count per node
  for (int i = tid; i < tot; i += 256) atomicAdd(&cnt[ebuf[i] >> 16], 1);
  __syncthreads();

  // node exclusive scan (wave 0, 1 elem/lane)
  if (w == 0) {
    int c = cnt[lane];
    int inc = c;
#pragma unroll
    for (int off = 1; off < 64; off <<= 1) {
      int t = __shfl_up(inc, off);
      if (lane >= off) inc += t;
    }
    nstart[lane] = inc - c;
  }
  __syncthreads();

  if (tid < BKN) {
    cur[tid] = nstart[tid];
    int node = node0 + tid;
    if (node < n_nodes) {
      offsets[node] = base + nstart[tid];
      ends[node] = base + nstart[tid] + cnt[tid];
    }
  }
  __syncthreads();

  for (int i = tid; i < tot; i += 256) {
    unsigned p = ebuf[i];
    int pos = atomicAdd(&cur[p >> 16], 1);
    sorted[(size_t)base + pos] = p;
  }
}

// ---------------------------------------------------------------------------
// Accum (R8-verified): wave per dst node, pure-vector register accumulation,
// 8-deep branch-free unroll.
// ---------------------------------------------------------------------------
__global__ __launch_bounds__(256) void accum_sorted_kernel(
    const int* __restrict__ offsets, const int* __restrict__ ends,
    const unsigned* __restrict__ sorted, const float* __restrict__ explog,
    const unsigned* __restrict__ nbf32, float* __restrict__ out, int n_nodes) {
  int node = (blockIdx.x * 256 + threadIdx.x) >> 6;
  int lane = threadIdx.x & 63;
  if (node >= n_nodes) return;
  int beg = offsets[node], end = ends[node];
  int last = end - 1;
  float acc0 = 0.f, acc1 = 0.f, den = 0.f;
  for (int e = beg; e < end; e += 8) {
    unsigned p[8];
    float x[8];
    unsigned u[8];
#pragma unroll
    for (int i = 0; i < 8; ++i) {
      int ei = e + i;
      int ec = (ei < last) ? ei : last;
      p[i] = sorted[ec];
    }
#pragma unroll
    for (int i = 0; i < 8; ++i) {
      int si = p[i] & 0xFFFF;
      u[i] = nbf32[(size_t)si * 64 + lane];
      x[i] = explog[si];
    }
#pragma unroll
    for (int i = 0; i < 8; ++i) {
      float xi = (e + i < end) ? x[i] : 0.f;
      den += xi;
      acc0 += xi * __uint_as_float(u[i] << 16);
      acc1 += xi * __uint_as_float(u[i] & 0xFFFF0000u);
    }
  }
  float inv = (end > beg) ? 1.0f / den : 0.f;
  *(float2*)(out + (size_t)node * D + lane * 2) =
      make_float2(acc0 * inv, acc1 * inv);
}

// ---------------------------------------------------------------------------
// Fallback path: scalar logit + per-edge atomics (R1, verified)
// ---------------------------------------------------------------------------
__global__ __launch_bounds__(256) void logit_kernel(
    const float* __restrict__ Nm, const float* __restrict__ W1,
    const float* __restrict__ w2, float* __restrict__ logit, int n_nodes) {
  __shared__ float w1t[32 * 129];
  const int tid = threadIdx.x;
  const int j = tid & 127;
  const int half = tid >> 7;
  const int base = blockIdx.x * NPB;
  float acc[8];
#pragma unroll
  for (int g = 0; g < 8; ++g) acc[g] = 0.f;
  for (int c = 0; c < 4; ++c) {
    __syncthreads();
    for (int idx = tid; idx < 128 * 32; idx += 256) {
      int kl = idx & 31, jj = idx >> 5;
      w1t[kl * 129 + jj] = W1[jj * 128 + c * 32 + kl];
    }
    __syncthreads();
#pragma unroll
    for (int g = 0; g < 8; ++g) {
      int node = base + g * 2 + half;
      if (node < n_nodes) {
        const float4* nrow =
            reinterpret_cast<const float4*>(Nm + (size_t)node * D + c * 32);
        float a = acc[g];
#pragma unroll
        for (int k4 = 0; k4 < 8; ++k4) {
          float4 nv = nrow[k4];
          int kl = k4 * 4;
          a += nv.x * w1t[(kl + 0) * 129 + j];
          a += nv.y * w1t[(kl + 1) * 129 + j];
          a += nv.z * w1t[(kl + 2) * 129 + j];
          a += nv.w * w1t[(kl + 3) * 129 + j];
        }
        acc[g] = a;
      }
    }
  }
  const float w2j = w2[j];
#pragma unroll
  for (int g = 0; g < 8; ++g) {
    int node = base + g * 2 + half;
    float t = tanhf(acc[g]) * w2j;
#pragma unroll
    for (int off = 32; off; off >>= 1) t += __shfl_down(t, off);
    if ((tid & 63) == 0 && node < n_nodes) atomicAdd(&logit[node], t);
  }
}

__global__ __launch_bounds__(256) void denom_kernel(
    const int* __restrict__ src, const int* __restrict__ dst,
    const float* __restrict__ logit, float* __restrict__ denom, int n_edges) {
  int e = blockIdx.x * 256 + threadIdx.x;
  if (e < n_edges) {
    float ex = expf(logit[src[e]]);
    atomicAdd(&denom[dst[e]], ex);
  }
}

__global__ __launch_bounds__(256) void scatter_kernel(
    const int* __restrict__ src, const int* __restrict__ dst,
    const float* __restrict__ logit, const float* __restrict__ denom,
    const float* __restrict__ Nm, float* __restrict__ out, int n_edges) {
  int wave = (blockIdx.x * 256 + threadIdx.x) >> 6;
  int lane = threadIdx.x & 63;
  if (wave >= n_edges) return;
  int s = src[wave];
  int d = dst[wave];
  float a = expf(logit[s]) / denom[d];
  float v0 = Nm[(size_t)s * D + lane];
  float v1 = Nm[(size_t)s * D + 64 + lane];
  atomicAdd(&out[(size_t)d * D + lane], a * v0);
  atomicAdd(&out[(size_t)d * D + 64 + lane], a * v1);
}

static inline char* align_up(char* p, size_t a) {
  return (char*)(((uintptr_t)p + a - 1) & ~(uintptr_t)(a - 1));
}

extern "C" void kernel_launch(void* const* d_in, const int* in_sizes, int n_in,
                              void* d_out, int out_size, void* d_ws,
                              size_t ws_size, hipStream_t stream) {
  const float* Nm  = (const float*)d_in[0];
  const float* W1  = (const float*)d_in[1];
  const float* w2  = (const float*)d_in[2];
  const int*   src = (const int*)d_in[3];
  const int*   dst = (const int*)d_in[4];
  float* out = (float*)d_out;

  const int n_nodes = in_sizes[0] / D;
  const int n_edges = in_sizes[3];
  const int n_pad = (n_nodes + 63) & ~63;
  const int nbuck = (n_nodes + BKN - 1) / BKN;
  const int nblk_bin = (n_edges + CHUNK - 1) / CHUNK;

  // carve workspace
  char* p = (char*)d_ws;
  float* explog = (float*)p;     p = align_up(p + (size_t)n_pad * 4, 256);
  float* denomF = (float*)p;     p = align_up(p + (size_t)n_pad * 4, 256);
  unsigned short* nbf = (unsigned short*)p;
  p = align_up(p + (size_t)n_nodes * D * 2, 256);
  unsigned* binout = (unsigned*)p;
  p = align_up(p + (size_t)nblk_bin * CHUNK * 4, 256);
  unsigned short* dir = (unsigned short*)p;
  p = align_up(p + (size_t)nblk_bin * (nbuck + 1) * 2, 256);
  unsigned* sorted = (unsigned*)p;
  p = align_up(p + (size_t)nbuck * CAP * 4, 256);
  int* offsets = (int*)p;        p = align_up(p + (size_t)n_pad * 4, 256);
  int* ends    = (int*)p;        p = align_up(p + (size_t)n_pad * 4, 256);
  size_t needed = (size_t)(p - (char*)d_ws);

  const bool fits = (ws_size >= needed) && (n_nodes <= 65535) &&
                    (nbuck <= MAXBUCK) && (nblk_bin <= NCHUNK_MAX) &&
                    ((n_edges / (nbuck > 0 ? nbuck : 1)) * 3 < CAP);

  if (fits) {
    // stage 1: logit chain ∥ bin counting sort (one launch, role split)
    int nblk1 = (n_nodes + 63) / 64;
    logit_bin_kernel<<<nblk1 + nblk_bin, 256, 0, stream>>>(
        Nm, W1, w2, explog, nbf, n_nodes, src, dst, binout, dir, n_edges,
        nbuck, nblk1);

    // stage 2: per-bucket merge (private windows, wave-scan)
    merge_kernel<<<nbuck, 256, 0, stream>>>(binout, dir, sorted, offsets,
                                            ends, n_nodes, nbuck, nblk_bin);

    // stage 3: accumulation (wave per node, 8-deep vector gather pipeline)
    int ablk = (n_nodes + 3) / 4;
    accum_sorted_kernel<<<ablk, 256, 0, stream>>>(
        offsets, ends, sorted, explog, (const unsigned*)nbf, out, n_nodes);
  } else {
    // fallback: scalar logit + R1 atomic path
    float* logit = explog;
    float* denom = denomF;
    hipMemsetAsync(logit, 0, (size_t)n_pad * sizeof(float), stream);
    hipMemsetAsync(denom, 0, (size_t)n_pad * sizeof(float), stream);
    hipMemsetAsync(out, 0, (size_t)out_size * sizeof(float), stream);
    int nblk1 = (n_nodes + NPB - 1) / NPB;
    logit_kernel<<<nblk1, 256, 0, stream>>>(Nm, W1, w2, logit, n_nodes);
    int eblk = (n_edges + 255) / 256;
    denom_kernel<<<eblk, 256, 0, stream>>>(src, dst, logit, denom, n_edges);
    int nblk3 = (n_edges + 3) / 4;
    scatter_kernel<<<nblk3, 256, 0, stream>>>(src, dst, logit, denom, Nm, out,
                                              n_edges);
  }
}

// Round 11
// 82.409 us; speedup vs baseline: 1.4978x; 1.0800x over previous
//
#include <hip/hip_runtime.h>
#include <hip/hip_bf16.h>

#define D 128
#define NPB 16           // nodes per block in fallback logit kernel
#define CHUNK 6144       // edges per bin block (24KB ebuf -> 33KB union -> 4 blk/CU)
#define BKN 64           // dst nodes per bucket
#define MAXBUCK 1024     // max buckets
#define NCHUNK_MAX 192   // max bin chunks supported by merge
#define CAP 4096         // per-bucket window & merge LDS buffer (avg ~1024)

typedef __attribute__((ext_vector_type(8))) short bf16x8;
typedef __attribute__((ext_vector_type(4))) float f32x4;

__device__ __forceinline__ unsigned short f2bf_rne(float f) {
  unsigned u = __float_as_uint(f);
  unsigned r = (u + 0x7FFFu + ((u >> 16) & 1u)) >> 16;
  return (unsigned short)r;
}

__device__ __forceinline__ float fast_tanh(float x) {
  float e = __expf(2.0f * x);
  return 1.0f - 2.0f / (e + 1.0f);
}

__device__ __forceinline__ void split8(const float* __restrict__ p,
                                       bf16x8& hv, bf16x8& lv) {
  float4 a = *(const float4*)p;
  float4 b = *(const float4*)(p + 4);
  float xs[8] = {a.x, a.y, a.z, a.w, b.x, b.y, b.z, b.w};
#pragma unroll
  for (int i = 0; i < 8; ++i) {
    unsigned short h = f2bf_rne(xs[i]);
    float hf = __uint_as_float((unsigned)h << 16);
    hv[i] = (short)h;
    lv[i] = (short)f2bf_rne(xs[i] - hf);
  }
}

struct SMLogit {
  unsigned short lhi[64 * 128];
  unsigned short llo[64 * 128];
  float part[4][64];
};
struct SMBin {
  unsigned cnt[MAXBUCK];
  unsigned cur[MAXBUCK];
  unsigned ebuf[CHUNK];
  int sdata[256];
};
union SMU {
  SMLogit lg;
  SMBin bn;
};

// ---------------------------------------------------------------------------
// Combined kernel, bin-first grid order: blocks [0, nblk_bin) run the bin
// counting sort (memory-bound, starts immediately); blocks [nblk_bin, ...)
// run the logit chain. Union LDS 33.3KB -> 4 blocks/CU -> whole grid (913
// blocks) co-resident in ONE generation.
// ---------------------------------------------------------------------------
__global__ __launch_bounds__(256, 2) void logit_bin_kernel(
    const float* __restrict__ Nm, const float* __restrict__ W1,
    const float* __restrict__ w2, float* __restrict__ explog,
    unsigned short* __restrict__ nbf, int n_nodes,
    const int* __restrict__ src, const int* __restrict__ dst,
    unsigned* __restrict__ binout, unsigned short* __restrict__ dir,
    int n_edges, int nbuck, int nblk_bin) {
  __shared__ SMU sm;
  const int tid = threadIdx.x;

  if ((int)blockIdx.x < nblk_bin) {
    // ================= bin role (R6-verified) =================
    const int blk = (int)blockIdx.x;
    const int ebase = blk * CHUNK;
    const int chunkN = min(CHUNK, n_edges - ebase);

    for (int i = tid; i < MAXBUCK; i += 256) sm.bn.cnt[i] = 0;
    __syncthreads();

    for (int i = tid; i < chunkN; i += 256) {
      int d = dst[ebase + i];
      atomicAdd(&sm.bn.cnt[d >> 6], 1u);
    }
    __syncthreads();

    int t4 = tid * 4;
    int c0 = sm.bn.cnt[t4], c1 = sm.bn.cnt[t4 + 1];
    int c2 = sm.bn.cnt[t4 + 2], c3 = sm.bn.cnt[t4 + 3];
    int s = c0 + c1 + c2 + c3;
    sm.bn.sdata[tid] = s;
    __syncthreads();
    for (int d = 1; d < 256; d <<= 1) {
      int v = (tid >= d) ? sm.bn.sdata[tid - d] : 0;
      __syncthreads();
      sm.bn.sdata[tid] += v;
      __syncthreads();
    }
    int tb = sm.bn.sdata[tid] - s;
    sm.bn.cur[t4] = tb;
    sm.bn.cur[t4 + 1] = tb + c0;
    sm.bn.cur[t4 + 2] = tb + c0 + c1;
    sm.bn.cur[t4 + 3] = tb + c0 + c1 + c2;
    __syncthreads();

    size_t dbase = (size_t)blk * (nbuck + 1);
    for (int k = tid; k < nbuck; k += 256)
      dir[dbase + k] = (unsigned short)sm.bn.cur[k];
    if (tid == 0) dir[dbase + nbuck] = (unsigned short)chunkN;
    __syncthreads();

    for (int i = tid; i < chunkN; i += 256) {
      int d = dst[ebase + i];
      int sv = src[ebase + i];
      unsigned slot = atomicAdd(&sm.bn.cur[d >> 6], 1u);
      sm.bn.ebuf[slot] = (unsigned)sv | ((unsigned)(d & 63) << 16);
    }
    __syncthreads();

    for (int i = tid; i < chunkN; i += 256) binout[ebase + i] = sm.bn.ebuf[i];
  } else {
    // ================= logit role (R8-verified) =================
    const int w = tid >> 6;
    const int l = tid & 63;
    const int lg = l >> 4;
    const int ln = l & 15;
    const int base = ((int)blockIdx.x - nblk_bin) * 64;

    bf16x8 Bh[2][4], Bl[2][4];
#pragma unroll
    for (int ntl = 0; ntl < 2; ++ntl) {
      int n = (w * 2 + ntl) * 16 + ln;
#pragma unroll
      for (int kt = 0; kt < 4; ++kt) {
        int k = kt * 32 + lg * 8;
        split8(W1 + n * 128 + k, Bh[ntl][kt], Bl[ntl][kt]);
      }
    }

#pragma unroll
    for (int i = 0; i < 8; ++i) {
      int flat = tid + i * 256;
      int row = flat >> 5;
      int c4 = flat & 31;
      int grow = base + row;
      if (grow >= n_nodes) grow = n_nodes - 1;
      float4 v = *(const float4*)(Nm + (size_t)grow * D + c4 * 4);
      unsigned short h0 = f2bf_rne(v.x), h1 = f2bf_rne(v.y);
      unsigned short h2 = f2bf_rne(v.z), h3 = f2bf_rne(v.w);
      unsigned short o0 = f2bf_rne(v.x - __uint_as_float((unsigned)h0 << 16));
      unsigned short o1 = f2bf_rne(v.y - __uint_as_float((unsigned)h1 << 16));
      unsigned short o2 = f2bf_rne(v.z - __uint_as_float((unsigned)h2 << 16));
      unsigned short o3 = f2bf_rne(v.w - __uint_as_float((unsigned)h3 << 16));
      int boff = (c4 * 8) ^ ((row & 7) << 4);
      *(ushort4*)((char*)sm.lg.lhi + row * 256 + boff) =
          make_ushort4(h0, h1, h2, h3);
      *(ushort4*)((char*)sm.lg.llo + row * 256 + boff) =
          make_ushort4(o0, o1, o2, o3);
      *(ushort4*)(nbf + (size_t)grow * D + c4 * 4) =
          make_ushort4(h0, h1, h2, h3);
    }
    __syncthreads();

    f32x4 acc[4][2];
#pragma unroll
    for (int mt = 0; mt < 4; ++mt)
#pragma unroll
      for (int ntl = 0; ntl < 2; ++ntl)
        acc[mt][ntl] = (f32x4){0.f, 0.f, 0.f, 0.f};

#pragma unroll
    for (int mt = 0; mt < 4; ++mt) {
      int row = mt * 16 + ln;
      bf16x8 Ah[4], Al[4];
#pragma unroll
      for (int kt = 0; kt < 4; ++kt) {
        int boff = (kt * 64 + lg * 16) ^ ((row & 7) << 4);
        Ah[kt] = *(const bf16x8*)((const char*)sm.lg.lhi + row * 256 + boff);
        Al[kt] = *(const bf16x8*)((const char*)sm.lg.llo + row * 256 + boff);
      }
#pragma unroll
      for (int ntl = 0; ntl < 2; ++ntl) {
#pragma unroll
        for (int kt = 0; kt < 4; ++kt) {
          acc[mt][ntl] = __builtin_amdgcn_mfma_f32_16x16x32_bf16(
              Ah[kt], Bh[ntl][kt], acc[mt][ntl], 0, 0, 0);
          acc[mt][ntl] = __builtin_amdgcn_mfma_f32_16x16x32_bf16(
              Ah[kt], Bl[ntl][kt], acc[mt][ntl], 0, 0, 0);
          acc[mt][ntl] = __builtin_amdgcn_mfma_f32_16x16x32_bf16(
              Al[kt], Bh[ntl][kt], acc[mt][ntl], 0, 0, 0);
        }
      }
    }

    float w2a = w2[(w * 2 + 0) * 16 + ln];
    float w2b = w2[(w * 2 + 1) * 16 + ln];
#pragma unroll
    for (int mt = 0; mt < 4; ++mt) {
      float s0 =
          fast_tanh(acc[mt][0][0]) * w2a + fast_tanh(acc[mt][1][0]) * w2b;
      float s1 =
          fast_tanh(acc[mt][0][1]) * w2a + fast_tanh(acc[mt][1][1]) * w2b;
      float s2 =
          fast_tanh(acc[mt][0][2]) * w2a + fast_tanh(acc[mt][1][2]) * w2b;
      float s3 =
          fast_tanh(acc[mt][0][3]) * w2a + fast_tanh(acc[mt][1][3]) * w2b;
#pragma unroll
      for (int mask = 1; mask < 16; mask <<= 1) {
        s0 += __shfl_xor(s0, mask);
        s1 += __shfl_xor(s1, mask);
        s2 += __shfl_xor(s2, mask);
        s3 += __shfl_xor(s3, mask);
      }
      if (ln < 4) {
        float sv = (ln == 0) ? s0 : (ln == 1) ? s1 : (ln == 2) ? s2 : s3;
        sm.lg.part[w][mt * 16 + lg * 4 + ln] = sv;
      }
    }
    __syncthreads();
    if (tid < 64) {
      int node = base + tid;
      if (node < n_nodes) {
        float t = sm.lg.part[0][tid] + sm.lg.part[1][tid] +
                  sm.lg.part[2][tid] + sm.lg.part[3][tid];
        explog[node] = expf(t);
      }
    }
  }
}

// ---------------------------------------------------------------------------
// Merge: one block per bucket -> private fixed window sorted[bk*CAP ...].
// Wave-scan (3 elems/lane, supports 192 chunks).
// ---------------------------------------------------------------------------
__global__ __launch_bounds__(256) void merge_kernel(
    const unsigned* __restrict__ binout, const unsigned short* __restrict__ dir,
    unsigned* __restrict__ sorted, int* __restrict__ offsets,
    int* __restrict__ ends, int n_nodes, int nbuck, int nblk_bin) {
  __shared__ unsigned ebuf[CAP];
  __shared__ int lens[NCHUNK_MAX], cstart[NCHUNK_MAX], ls0[NCHUNK_MAX];
  __shared__ int cnt[BKN], nstart[BKN], cur[BKN];
  __shared__ int total;
  const int tid = threadIdx.x;
  const int w = tid >> 6, lane = tid & 63;
  const int bk = blockIdx.x;
  const int node0 = bk * BKN;
  const int base = bk * CAP;

  if (tid < nblk_bin) {
    size_t dbase = (size_t)tid * (nbuck + 1);
    int s0 = dir[dbase + bk];
    int s1 = dir[dbase + bk + 1];
    ls0[tid] = s0;
    lens[tid] = s1 - s0;
  }
  if (tid < BKN) cnt[tid] = 0;
  __syncthreads();

  // chunk exclusive scan (wave 0, 3 elems/lane, shfl_up)
  if (w == 0) {
    int l0 = lane * 3, l1 = l0 + 1, l2 = l0 + 2;
    int a = (l0 < nblk_bin) ? lens[l0] : 0;
    int b = (l1 < nblk_bin) ? lens[l1] : 0;
    int c = (l2 < nblk_bin) ? lens[l2] : 0;
    int sv = a + b + c;
    int inc = sv;
#pragma unroll
    for (int off = 1; off < 64; off <<= 1) {
      int t = __shfl_up(inc, off);
      if (lane >= off) inc += t;
    }
    int ex = inc - sv;
    if (l0 < nblk_bin) cstart[l0] = ex;
    if (l1 < nblk_bin) cstart[l1] = ex + a;
    if (l2 < nblk_bin) cstart[l2] = ex + a + b;
    if (lane == 63) total = (inc > CAP) ? CAP : inc;
  }
  __syncthreads();
  const int tot = total;

  // gather runs
  for (int r = w; r < nblk_bin; r += 4) {
    int len = lens[r], cs = cstart[r];
    if (cs >= CAP) continue;
    if (cs + len > CAP) len = CAP - cs;
    const unsigned* g = binout + (size_t)r * CHUNK + ls0[r];
    for (int i = lane; i < len; i += 64) ebuf[cs + i] = g[i];
  }
  __syncthreads();

  // count per node
  for (int i = tid; i < tot; i += 256) atomicAdd(&cnt[ebuf[i] >> 16], 1);
  __syncthreads();

  // node exclusive scan (wave 0, 1 elem/lane)
  if (w == 0) {
    int c = cnt[lane];
    int inc = c;
#pragma unroll
    for (int off = 1; off < 64; off <<= 1) {
      int t = __shfl_up(inc, off);
      if (lane >= off) inc += t;
    }
    nstart[lane] = inc - c;
  }
  __syncthreads();

  if (tid < BKN) {
    cur[tid] = nstart[tid];
    int node = node0 + tid;
    if (node < n_nodes) {
      offsets[node] = base + nstart[tid];
      ends[node] = base + nstart[tid] + cnt[tid];
    }
  }
  __syncthreads();

  for (int i = tid; i < tot; i += 256) {
    unsigned p = ebuf[i];
    int pos = atomicAdd(&cur[p >> 16], 1);
    sorted[(size_t)base + pos] = p;
  }
}

// ---------------------------------------------------------------------------
// Accum (R8-verified): wave per dst node, pure-vector register accumulation,
// 8-deep branch-free unroll.
// ---------------------------------------------------------------------------
__global__ __launch_bounds__(256) void accum_sorted_kernel(
    const int* __restrict__ offsets, const int* __restrict__ ends,
    const unsigned* __restrict__ sorted, const float* __restrict__ explog,
    const unsigned* __restrict__ nbf32, float* __restrict__ out, int n_nodes) {
  int node = (blockIdx.x * 256 + threadIdx.x) >> 6;
  int lane = threadIdx.x & 63;
  if (node >= n_nodes) return;
  int beg = offsets[node], end = ends[node];
  int last = end - 1;
  float acc0 = 0.f, acc1 = 0.f, den = 0.f;
  for (int e = beg; e < end; e += 8) {
    unsigned p[8];
    float x[8];
    unsigned u[8];
#pragma unroll
    for (int i = 0; i < 8; ++i) {
      int ei = e + i;
      int ec = (ei < last) ? ei : last;
      p[i] = sorted[ec];
    }
#pragma unroll
    for (int i = 0; i < 8; ++i) {
      int si = p[i] & 0xFFFF;
      u[i] = nbf32[(size_t)si * 64 + lane];
      x[i] = explog[si];
    }
#pragma unroll
    for (int i = 0; i < 8; ++i) {
      float xi = (e + i < end) ? x[i] : 0.f;
      den += xi;
      acc0 += xi * __uint_as_float(u[i] << 16);
      acc1 += xi * __uint_as_float(u[i] & 0xFFFF0000u);
    }
  }
  float inv = (end > beg) ? 1.0f / den : 0.f;
  *(float2*)(out + (size_t)node * D + lane * 2) =
      make_float2(acc0 * inv, acc1 * inv);
}

// ---------------------------------------------------------------------------
// Fallback path: scalar logit + per-edge atomics (R1, verified)
// ---------------------------------------------------------------------------
__global__ __launch_bounds__(256) void logit_kernel(
    const float* __restrict__ Nm, const float* __restrict__ W1,
    const float* __restrict__ w2, float* __restrict__ logit, int n_nodes) {
  __shared__ float w1t[32 * 129];
  const int tid = threadIdx.x;
  const int j = tid & 127;
  const int half = tid >> 7;
  const int base = blockIdx.x * NPB;
  float acc[8];
#pragma unroll
  for (int g = 0; g < 8; ++g) acc[g] = 0.f;
  for (int c = 0; c < 4; ++c) {
    __syncthreads();
    for (int idx = tid; idx < 128 * 32; idx += 256) {
      int kl = idx & 31, jj = idx >> 5;
      w1t[kl * 129 + jj] = W1[jj * 128 + c * 32 + kl];
    }
    __syncthreads();
#pragma unroll
    for (int g = 0; g < 8; ++g) {
      int node = base + g * 2 + half;
      if (node < n_nodes) {
        const float4* nrow =
            reinterpret_cast<const float4*>(Nm + (size_t)node * D + c * 32);
        float a = acc[g];
#pragma unroll
        for (int k4 = 0; k4 < 8; ++k4) {
          float4 nv = nrow[k4];
          int kl = k4 * 4;
          a += nv.x * w1t[(kl + 0) * 129 + j];
          a += nv.y * w1t[(kl + 1) * 129 + j];
          a += nv.z * w1t[(kl + 2) * 129 + j];
          a += nv.w * w1t[(kl + 3) * 129 + j];
        }
        acc[g] = a;
      }
    }
  }
  const float w2j = w2[j];
#pragma unroll
  for (int g = 0; g < 8; ++g) {
    int node = base + g * 2 + half;
    float t = tanhf(acc[g]) * w2j;
#pragma unroll
    for (int off = 32; off; off >>= 1) t += __shfl_down(t, off);
    if ((tid & 63) == 0 && node < n_nodes) atomicAdd(&logit[node], t);
  }
}

__global__ __launch_bounds__(256) void denom_kernel(
    const int* __restrict__ src, const int* __restrict__ dst,
    const float* __restrict__ logit, float* __restrict__ denom, int n_edges) {
  int e = blockIdx.x * 256 + threadIdx.x;
  if (e < n_edges) {
    float ex = expf(logit[src[e]]);
    atomicAdd(&denom[dst[e]], ex);
  }
}

__global__ __launch_bounds__(256) void scatter_kernel(
    const int* __restrict__ src, const int* __restrict__ dst,
    const float* __restrict__ logit, const float* __restrict__ denom,
    const float* __restrict__ Nm, float* __restrict__ out, int n_edges) {
  int wave = (blockIdx.x * 256 + threadIdx.x) >> 6;
  int lane = threadIdx.x & 63;
  if (wave >= n_edges) return;
  int s = src[wave];
  int d = dst[wave];
  float a = expf(logit[s]) / denom[d];
  float v0 = Nm[(size_t)s * D + lane];
  float v1 = Nm[(size_t)s * D + 64 + lane];
  atomicAdd(&out[(size_t)d * D + lane], a * v0);
  atomicAdd(&out[(size_t)d * D + 64 + lane], a * v1);
}

static inline char* align_up(char* p, size_t a) {
  return (char*)(((uintptr_t)p + a - 1) & ~(uintptr_t)(a - 1));
}

extern "C" void kernel_launch(void* const* d_in, const int* in_sizes, int n_in,
                              void* d_out, int out_size, void* d_ws,
                              size_t ws_size, hipStream_t stream) {
  const float* Nm  = (const float*)d_in[0];
  const float* W1  = (const float*)d_in[1];
  const float* w2  = (const float*)d_in[2];
  const int*   src = (const int*)d_in[3];
  const int*   dst = (const int*)d_in[4];
  float* out = (float*)d_out;

  const int n_nodes = in_sizes[0] / D;
  const int n_edges = in_sizes[3];
  const int n_pad = (n_nodes + 63) & ~63;
  const int nbuck = (n_nodes + BKN - 1) / BKN;
  const int nblk_bin = (n_edges + CHUNK - 1) / CHUNK;

  // carve workspace
  char* p = (char*)d_ws;
  float* explog = (float*)p;     p = align_up(p + (size_t)n_pad * 4, 256);
  float* denomF = (float*)p;     p = align_up(p + (size_t)n_pad * 4, 256);
  unsigned short* nbf = (unsigned short*)p;
  p = align_up(p + (size_t)n_nodes * D * 2, 256);
  unsigned* binout = (unsigned*)p;
  p = align_up(p + (size_t)nblk_bin * CHUNK * 4, 256);
  unsigned short* dir = (unsigned short*)p;
  p = align_up(p + (size_t)nblk_bin * (nbuck + 1) * 2, 256);
  unsigned* sorted = (unsigned*)p;
  p = align_up(p + (size_t)nbuck * CAP * 4, 256);
  int* offsets = (int*)p;        p = align_up(p + (size_t)n_pad * 4, 256);
  int* ends    = (int*)p;        p = align_up(p + (size_t)n_pad * 4, 256);
  size_t needed = (size_t)(p - (char*)d_ws);

  const bool fits = (ws_size >= needed) && (n_nodes <= 65535) &&
                    (nbuck <= MAXBUCK) && (nblk_bin <= NCHUNK_MAX) &&
                    ((n_edges / (nbuck > 0 ? nbuck : 1)) * 3 < CAP);

  if (fits) {
    // stage 1: bin counting sort ∥ logit chain (one launch, bin-first order,
    // fully co-resident grid)
    int nblk1 = (n_nodes + 63) / 64;
    logit_bin_kernel<<<nblk_bin + nblk1, 256, 0, stream>>>(
        Nm, W1, w2, explog, nbf, n_nodes, src, dst, binout, dir, n_edges,
        nbuck, nblk_bin);

    // stage 2: per-bucket merge (private windows, wave-scan)
    merge_kernel<<<nbuck, 256, 0, stream>>>(binout, dir, sorted, offsets,
                                            ends, n_nodes, nbuck, nblk_bin);

    // stage 3: accumulation (wave per node, 8-deep vector gather pipeline)
    int ablk = (n_nodes + 3) / 4;
    accum_sorted_kernel<<<ablk, 256, 0, stream>>>(
        offsets, ends, sorted, explog, (const unsigned*)nbf, out, n_nodes);
  } else {
    // fallback: scalar logit + R1 atomic path
    float* logit = explog;
    float* denom = denomF;
    hipMemsetAsync(logit, 0, (size_t)n_pad * sizeof(float), stream);
    hipMemsetAsync(denom, 0, (size_t)n_pad * sizeof(float), stream);
    hipMemsetAsync(out, 0, (size_t)out_size * sizeof(float), stream);
    int nblk1 = (n_nodes + NPB - 1) / NPB;
    logit_kernel<<<nblk1, 256, 0, stream>>>(Nm, W1, w2, logit, n_nodes);
    int eblk = (n_edges + 255) / 256;
    denom_kernel<<<eblk, 256, 0, stream>>>(src, dst, logit, denom, n_edges);
    int nblk3 = (n_edges + 3) / 4;
    scatter_kernel<<<nblk3, 256, 0, stream>>>(src, dst, logit, denom, Nm, out,
                                              n_edges);
  }
}

// Round 12
// 81.350 us; speedup vs baseline: 1.5173x; 1.0130x over previous
//
#include <hip/hip_runtime.h>
#include <hip/hip_bf16.h>

#define D 128
#define NPB 16           // nodes per block in fallback logit kernel
#define CHUNK 6144       // edges per bin block (24KB ebuf -> 33KB union -> 4 blk/CU)
#define BKN 64           // dst nodes per bucket
#define MAXBUCK 1024     // max buckets
#define NCHUNK_MAX 192   // max bin chunks supported by merge
#define CAP 4096         // per-bucket window & merge LDS buffer (avg ~1024)

typedef __attribute__((ext_vector_type(8))) short bf16x8;
typedef __attribute__((ext_vector_type(4))) float f32x4;

__device__ __forceinline__ unsigned short f2bf_rne(float f) {
  unsigned u = __float_as_uint(f);
  unsigned r = (u + 0x7FFFu + ((u >> 16) & 1u)) >> 16;
  return (unsigned short)r;
}

__device__ __forceinline__ float fast_tanh(float x) {
  float e = __expf(2.0f * x);
  return 1.0f - 2.0f / (e + 1.0f);
}

__device__ __forceinline__ void split8(const float* __restrict__ p,
                                       bf16x8& hv, bf16x8& lv) {
  float4 a = *(const float4*)p;
  float4 b = *(const float4*)(p + 4);
  float xs[8] = {a.x, a.y, a.z, a.w, b.x, b.y, b.z, b.w};
#pragma unroll
  for (int i = 0; i < 8; ++i) {
    unsigned short h = f2bf_rne(xs[i]);
    float hf = __uint_as_float((unsigned)h << 16);
    hv[i] = (short)h;
    lv[i] = (short)f2bf_rne(xs[i] - hf);
  }
}

struct SMLogit {
  unsigned short lhi[64 * 128];
  unsigned short llo[64 * 128];
  float part[4][64];
};
struct SMBin {
  unsigned cnt[MAXBUCK];
  unsigned cur[MAXBUCK];
  unsigned ebuf[CHUNK];
  int sdata[256];
};
union SMU {
  SMLogit lg;
  SMBin bn;
};

// ---------------------------------------------------------------------------
// Combined kernel (R11-verified), bin-first grid order, fully co-resident.
// ---------------------------------------------------------------------------
__global__ __launch_bounds__(256, 2) void logit_bin_kernel(
    const float* __restrict__ Nm, const float* __restrict__ W1,
    const float* __restrict__ w2, float* __restrict__ explog,
    unsigned short* __restrict__ nbf, int n_nodes,
    const int* __restrict__ src, const int* __restrict__ dst,
    unsigned* __restrict__ binout, unsigned short* __restrict__ dir,
    int n_edges, int nbuck, int nblk_bin) {
  __shared__ SMU sm;
  const int tid = threadIdx.x;

  if ((int)blockIdx.x < nblk_bin) {
    // ================= bin role =================
    const int blk = (int)blockIdx.x;
    const int ebase = blk * CHUNK;
    const int chunkN = min(CHUNK, n_edges - ebase);

    for (int i = tid; i < MAXBUCK; i += 256) sm.bn.cnt[i] = 0;
    __syncthreads();

    for (int i = tid; i < chunkN; i += 256) {
      int d = dst[ebase + i];
      atomicAdd(&sm.bn.cnt[d >> 6], 1u);
    }
    __syncthreads();

    int t4 = tid * 4;
    int c0 = sm.bn.cnt[t4], c1 = sm.bn.cnt[t4 + 1];
    int c2 = sm.bn.cnt[t4 + 2], c3 = sm.bn.cnt[t4 + 3];
    int s = c0 + c1 + c2 + c3;
    sm.bn.sdata[tid] = s;
    __syncthreads();
    for (int d = 1; d < 256; d <<= 1) {
      int v = (tid >= d) ? sm.bn.sdata[tid - d] : 0;
      __syncthreads();
      sm.bn.sdata[tid] += v;
      __syncthreads();
    }
    int tb = sm.bn.sdata[tid] - s;
    sm.bn.cur[t4] = tb;
    sm.bn.cur[t4 + 1] = tb + c0;
    sm.bn.cur[t4 + 2] = tb + c0 + c1;
    sm.bn.cur[t4 + 3] = tb + c0 + c1 + c2;
    __syncthreads();

    size_t dbase = (size_t)blk * (nbuck + 1);
    for (int k = tid; k < nbuck; k += 256)
      dir[dbase + k] = (unsigned short)sm.bn.cur[k];
    if (tid == 0) dir[dbase + nbuck] = (unsigned short)chunkN;
    __syncthreads();

    for (int i = tid; i < chunkN; i += 256) {
      int d = dst[ebase + i];
      int sv = src[ebase + i];
      unsigned slot = atomicAdd(&sm.bn.cur[d >> 6], 1u);
      sm.bn.ebuf[slot] = (unsigned)sv | ((unsigned)(d & 63) << 16);
    }
    __syncthreads();

    for (int i = tid; i < chunkN; i += 256) binout[ebase + i] = sm.bn.ebuf[i];
  } else {
    // ================= logit role =================
    const int w = tid >> 6;
    const int l = tid & 63;
    const int lg = l >> 4;
    const int ln = l & 15;
    const int base = ((int)blockIdx.x - nblk_bin) * 64;

    bf16x8 Bh[2][4], Bl[2][4];
#pragma unroll
    for (int ntl = 0; ntl < 2; ++ntl) {
      int n = (w * 2 + ntl) * 16 + ln;
#pragma unroll
      for (int kt = 0; kt < 4; ++kt) {
        int k = kt * 32 + lg * 8;
        split8(W1 + n * 128 + k, Bh[ntl][kt], Bl[ntl][kt]);
      }
    }

#pragma unroll
    for (int i = 0; i < 8; ++i) {
      int flat = tid + i * 256;
      int row = flat >> 5;
      int c4 = flat & 31;
      int grow = base + row;
      if (grow >= n_nodes) grow = n_nodes - 1;
      float4 v = *(const float4*)(Nm + (size_t)grow * D + c4 * 4);
      unsigned short h0 = f2bf_rne(v.x), h1 = f2bf_rne(v.y);
      unsigned short h2 = f2bf_rne(v.z), h3 = f2bf_rne(v.w);
      unsigned short o0 = f2bf_rne(v.x - __uint_as_float((unsigned)h0 << 16));
      unsigned short o1 = f2bf_rne(v.y - __uint_as_float((unsigned)h1 << 16));
      unsigned short o2 = f2bf_rne(v.z - __uint_as_float((unsigned)h2 << 16));
      unsigned short o3 = f2bf_rne(v.w - __uint_as_float((unsigned)h3 << 16));
      int boff = (c4 * 8) ^ ((row & 7) << 4);
      *(ushort4*)((char*)sm.lg.lhi + row * 256 + boff) =
          make_ushort4(h0, h1, h2, h3);
      *(ushort4*)((char*)sm.lg.llo + row * 256 + boff) =
          make_ushort4(o0, o1, o2, o3);
      *(ushort4*)(nbf + (size_t)grow * D + c4 * 4) =
          make_ushort4(h0, h1, h2, h3);
    }
    __syncthreads();

    f32x4 acc[4][2];
#pragma unroll
    for (int mt = 0; mt < 4; ++mt)
#pragma unroll
      for (int ntl = 0; ntl < 2; ++ntl)
        acc[mt][ntl] = (f32x4){0.f, 0.f, 0.f, 0.f};

#pragma unroll
    for (int mt = 0; mt < 4; ++mt) {
      int row = mt * 16 + ln;
      bf16x8 Ah[4], Al[4];
#pragma unroll
      for (int kt = 0; kt < 4; ++kt) {
        int boff = (kt * 64 + lg * 16) ^ ((row & 7) << 4);
        Ah[kt] = *(const bf16x8*)((const char*)sm.lg.lhi + row * 256 + boff);
        Al[kt] = *(const bf16x8*)((const char*)sm.lg.llo + row * 256 + boff);
      }
#pragma unroll
      for (int ntl = 0; ntl < 2; ++ntl) {
#pragma unroll
        for (int kt = 0; kt < 4; ++kt) {
          acc[mt][ntl] = __builtin_amdgcn_mfma_f32_16x16x32_bf16(
              Ah[kt], Bh[ntl][kt], acc[mt][ntl], 0, 0, 0);
          acc[mt][ntl] = __builtin_amdgcn_mfma_f32_16x16x32_bf16(
              Ah[kt], Bl[ntl][kt], acc[mt][ntl], 0, 0, 0);
          acc[mt][ntl] = __builtin_amdgcn_mfma_f32_16x16x32_bf16(
              Al[kt], Bh[ntl][kt], acc[mt][ntl], 0, 0, 0);
        }
      }
    }

    float w2a = w2[(w * 2 + 0) * 16 + ln];
    float w2b = w2[(w * 2 + 1) * 16 + ln];
#pragma unroll
    for (int mt = 0; mt < 4; ++mt) {
      float s0 =
          fast_tanh(acc[mt][0][0]) * w2a + fast_tanh(acc[mt][1][0]) * w2b;
      float s1 =
          fast_tanh(acc[mt][0][1]) * w2a + fast_tanh(acc[mt][1][1]) * w2b;
      float s2 =
          fast_tanh(acc[mt][0][2]) * w2a + fast_tanh(acc[mt][1][2]) * w2b;
      float s3 =
          fast_tanh(acc[mt][0][3]) * w2a + fast_tanh(acc[mt][1][3]) * w2b;
#pragma unroll
      for (int mask = 1; mask < 16; mask <<= 1) {
        s0 += __shfl_xor(s0, mask);
        s1 += __shfl_xor(s1, mask);
        s2 += __shfl_xor(s2, mask);
        s3 += __shfl_xor(s3, mask);
      }
      if (ln < 4) {
        float sv = (ln == 0) ? s0 : (ln == 1) ? s1 : (ln == 2) ? s2 : s3;
        sm.lg.part[w][mt * 16 + lg * 4 + ln] = sv;
      }
    }
    __syncthreads();
    if (tid < 64) {
      int node = base + tid;
      if (node < n_nodes) {
        float t = sm.lg.part[0][tid] + sm.lg.part[1][tid] +
                  sm.lg.part[2][tid] + sm.lg.part[3][tid];
        explog[node] = expf(t);
      }
    }
  }
}

// ---------------------------------------------------------------------------
// Merge (R11-verified): one block per bucket -> private window, wave-scan.
// ---------------------------------------------------------------------------
__global__ __launch_bounds__(256) void merge_kernel(
    const unsigned* __restrict__ binout, const unsigned short* __restrict__ dir,
    unsigned* __restrict__ sorted, int* __restrict__ offsets,
    int* __restrict__ ends, int n_nodes, int nbuck, int nblk_bin) {
  __shared__ unsigned ebuf[CAP];
  __shared__ int lens[NCHUNK_MAX], cstart[NCHUNK_MAX], ls0[NCHUNK_MAX];
  __shared__ int cnt[BKN], nstart[BKN], cur[BKN];
  __shared__ int total;
  const int tid = threadIdx.x;
  const int w = tid >> 6, lane = tid & 63;
  const int bk = blockIdx.x;
  const int node0 = bk * BKN;
  const int base = bk * CAP;

  if (tid < nblk_bin) {
    size_t dbase = (size_t)tid * (nbuck + 1);
    int s0 = dir[dbase + bk];
    int s1 = dir[dbase + bk + 1];
    ls0[tid] = s0;
    lens[tid] = s1 - s0;
  }
  if (tid < BKN) cnt[tid] = 0;
  __syncthreads();

  if (w == 0) {
    int l0 = lane * 3, l1 = l0 + 1, l2 = l0 + 2;
    int a = (l0 < nblk_bin) ? lens[l0] : 0;
    int b = (l1 < nblk_bin) ? lens[l1] : 0;
    int c = (l2 < nblk_bin) ? lens[l2] : 0;
    int sv = a + b + c;
    int inc = sv;
#pragma unroll
    for (int off = 1; off < 64; off <<= 1) {
      int t = __shfl_up(inc, off);
      if (lane >= off) inc += t;
    }
    int ex = inc - sv;
    if (l0 < nblk_bin) cstart[l0] = ex;
    if (l1 < nblk_bin) cstart[l1] = ex + a;
    if (l2 < nblk_bin) cstart[l2] = ex + a + b;
    if (lane == 63) total = (inc > CAP) ? CAP : inc;
  }
  __syncthreads();
  const int tot = total;

  for (int r = w; r < nblk_bin; r += 4) {
    int len = lens[r], cs = cstart[r];
    if (cs >= CAP) continue;
    if (cs + len > CAP) len = CAP - cs;
    const unsigned* g = binout + (size_t)r * CHUNK + ls0[r];
    for (int i = lane; i < len; i += 64) ebuf[cs + i] = g[i];
  }
  __syncthreads();

  for (int i = tid; i < tot; i += 256) atomicAdd(&cnt[ebuf[i] >> 16], 1);
  __syncthreads();

  if (w == 0) {
    int c = cnt[lane];
    int inc = c;
#pragma unroll
    for (int off = 1; off < 64; off <<= 1) {
      int t = __shfl_up(inc, off);
      if (lane >= off) inc += t;
    }
    nstart[lane] = inc - c;
  }
  __syncthreads();

  if (tid < BKN) {
    cur[tid] = nstart[tid];
    int node = node0 + tid;
    if (node < n_nodes) {
      offsets[node] = base + nstart[tid];
      ends[node] = base + nstart[tid] + cnt[tid];
    }
  }
  __syncthreads();

  for (int i = tid; i < tot; i += 256) {
    unsigned p = ebuf[i];
    int pos = atomicAdd(&cur[p >> 16], 1);
    sorted[(size_t)base + pos] = p;
  }
}

// ---------------------------------------------------------------------------
// Accum: wave per dst node, lane-split (eg=lane>>4 picks edge, fl=lane&15
// picks 8-feature block). Per 4 edges: 1 sorted dword gather + 1 explog
// dword gather + 1 nbf dwordx4 (16B/lane) gather. 2 groups (8 edges) in
// flight. Edge-groups combined via shfl_xor(16|32); each edge counted once.
// ---------------------------------------------------------------------------
__global__ __launch_bounds__(256) void accum_sorted_kernel(
    const int* __restrict__ offsets, const int* __restrict__ ends,
    const unsigned* __restrict__ sorted, const float* __restrict__ explog,
    const unsigned short* __restrict__ nbf, float* __restrict__ out,
    int n_nodes) {
  int node = (blockIdx.x * 256 + threadIdx.x) >> 6;
  int lane = threadIdx.x & 63;
  if (node >= n_nodes) return;
  const int eg = lane >> 4;  // edge slot 0..3
  const int fl = lane & 15;  // feature block 0..15 (8 features each)
  int beg = offsets[node], end = ends[node];
  int last = end - 1;
  float acc[8];
#pragma unroll
  for (int j = 0; j < 8; ++j) acc[j] = 0.f;
  float den = 0.f;

  for (int e = beg; e < end; e += 8) {
    int ea = e + eg;
    int eb = e + 4 + eg;
    int eca = (ea < last) ? ea : last;
    int ecb = (eb < last) ? eb : last;
    unsigned pa = sorted[eca];
    unsigned pb = sorted[ecb];
    int sa = pa & 0xFFFF, sb = pb & 0xFFFF;
    float xa = explog[sa];
    float xb = explog[sb];
    uint4 ua = *(const uint4*)(nbf + (size_t)sa * D + fl * 8);
    uint4 ub = *(const uint4*)(nbf + (size_t)sb * D + fl * 8);
    xa = (ea < end) ? xa : 0.f;
    xb = (eb < end) ? xb : 0.f;
    den += xa + xb;
    unsigned va[4] = {ua.x, ua.y, ua.z, ua.w};
    unsigned vb[4] = {ub.x, ub.y, ub.z, ub.w};
#pragma unroll
    for (int j = 0; j < 4; ++j) {
      acc[2 * j] += xa * __uint_as_float(va[j] << 16) +
                    xb * __uint_as_float(vb[j] << 16);
      acc[2 * j + 1] += xa * __uint_as_float(va[j] & 0xFFFF0000u) +
                        xb * __uint_as_float(vb[j] & 0xFFFF0000u);
    }
  }

  // combine the 4 edge-groups (lanes l, l^16, l^32, l^48 share fl)
#pragma unroll
  for (int j = 0; j < 8; ++j) {
    acc[j] += __shfl_xor(acc[j], 16);
    acc[j] += __shfl_xor(acc[j], 32);
  }
  den += __shfl_xor(den, 16);
  den += __shfl_xor(den, 32);

  if (eg == 0) {
    float inv = (end > beg) ? 1.0f / den : 0.f;
    float4 o0 = make_float4(acc[0] * inv, acc[1] * inv, acc[2] * inv,
                            acc[3] * inv);
    float4 o1 = make_float4(acc[4] * inv, acc[5] * inv, acc[6] * inv,
                            acc[7] * inv);
    float* orow = out + (size_t)node * D + fl * 8;
    *(float4*)orow = o0;
    *(float4*)(orow + 4) = o1;
  }
}

// ---------------------------------------------------------------------------
// Fallback path: scalar logit + per-edge atomics (R1, verified)
// ---------------------------------------------------------------------------
__global__ __launch_bounds__(256) void logit_kernel(
    const float* __restrict__ Nm, const float* __restrict__ W1,
    const float* __restrict__ w2, float* __restrict__ logit, int n_nodes) {
  __shared__ float w1t[32 * 129];
  const int tid = threadIdx.x;
  const int j = tid & 127;
  const int half = tid >> 7;
  const int base = blockIdx.x * NPB;
  float acc[8];
#pragma unroll
  for (int g = 0; g < 8; ++g) acc[g] = 0.f;
  for (int c = 0; c < 4; ++c) {
    __syncthreads();
    for (int idx = tid; idx < 128 * 32; idx += 256) {
      int kl = idx & 31, jj = idx >> 5;
      w1t[kl * 129 + jj] = W1[jj * 128 + c * 32 + kl];
    }
    __syncthreads();
#pragma unroll
    for (int g = 0; g < 8; ++g) {
      int node = base + g * 2 + half;
      if (node < n_nodes) {
        const float4* nrow =
            reinterpret_cast<const float4*>(Nm + (size_t)node * D + c * 32);
        float a = acc[g];
#pragma unroll
        for (int k4 = 0; k4 < 8; ++k4) {
          float4 nv = nrow[k4];
          int kl = k4 * 4;
          a += nv.x * w1t[(kl + 0) * 129 + j];
          a += nv.y * w1t[(kl + 1) * 129 + j];
          a += nv.z * w1t[(kl + 2) * 129 + j];
          a += nv.w * w1t[(kl + 3) * 129 + j];
        }
        acc[g] = a;
      }
    }
  }
  const float w2j = w2[j];
#pragma unroll
  for (int g = 0; g < 8; ++g) {
    int node = base + g * 2 + half;
    float t = tanhf(acc[g]) * w2j;
#pragma unroll
    for (int off = 32; off; off >>= 1) t += __shfl_down(t, off);
    if ((tid & 63) == 0 && node < n_nodes) atomicAdd(&logit[node], t);
  }
}

__global__ __launch_bounds__(256) void denom_kernel(
    const int* __restrict__ src, const int* __restrict__ dst,
    const float* __restrict__ logit, float* __restrict__ denom, int n_edges) {
  int e = blockIdx.x * 256 + threadIdx.x;
  if (e < n_edges) {
    float ex = expf(logit[src[e]]);
    atomicAdd(&denom[dst[e]], ex);
  }
}

__global__ __launch_bounds__(256) void scatter_kernel(
    const int* __restrict__ src, const int* __restrict__ dst,
    const float* __restrict__ logit, const float* __restrict__ denom,
    const float* __restrict__ Nm, float* __restrict__ out, int n_edges) {
  int wave = (blockIdx.x * 256 + threadIdx.x) >> 6;
  int lane = threadIdx.x & 63;
  if (wave >= n_edges) return;
  int s = src[wave];
  int d = dst[wave];
  float a = expf(logit[s]) / denom[d];
  float v0 = Nm[(size_t)s * D + lane];
  float v1 = Nm[(size_t)s * D + 64 + lane];
  atomicAdd(&out[(size_t)d * D + lane], a * v0);
  atomicAdd(&out[(size_t)d * D + 64 + lane], a * v1);
}

static inline char* align_up(char* p, size_t a) {
  return (char*)(((uintptr_t)p + a - 1) & ~(uintptr_t)(a - 1));
}

extern "C" void kernel_launch(void* const* d_in, const int* in_sizes, int n_in,
                              void* d_out, int out_size, void* d_ws,
                              size_t ws_size, hipStream_t stream) {
  const float* Nm  = (const float*)d_in[0];
  const float* W1  = (const float*)d_in[1];
  const float* w2  = (const float*)d_in[2];
  const int*   src = (const int*)d_in[3];
  const int*   dst = (const int*)d_in[4];
  float* out = (float*)d_out;

  const int n_nodes = in_sizes[0] / D;
  const int n_edges = in_sizes[3];
  const int n_pad = (n_nodes + 63) & ~63;
  const int nbuck = (n_nodes + BKN - 1) / BKN;
  const int nblk_bin = (n_edges + CHUNK - 1) / CHUNK;

  // carve workspace
  char* p = (char*)d_ws;
  float* explog = (float*)p;     p = align_up(p + (size_t)n_pad * 4, 256);
  float* denomF = (float*)p;     p = align_up(p + (size_t)n_pad * 4, 256);
  unsigned short* nbf = (unsigned short*)p;
  p = align_up(p + (size_t)n_nodes * D * 2, 256);
  unsigned* binout = (unsigned*)p;
  p = align_up(p + (size_t)nblk_bin * CHUNK * 4, 256);
  unsigned short* dir = (unsigned short*)p;
  p = align_up(p + (size_t)nblk_bin * (nbuck + 1) * 2, 256);
  unsigned* sorted = (unsigned*)p;
  p = align_up(p + (size_t)nbuck * CAP * 4, 256);
  int* offsets = (int*)p;        p = align_up(p + (size_t)n_pad * 4, 256);
  int* ends    = (int*)p;        p = align_up(p + (size_t)n_pad * 4, 256);
  size_t needed = (size_t)(p - (char*)d_ws);

  const bool fits = (ws_size >= needed) && (n_nodes <= 65535) &&
                    (nbuck <= MAXBUCK) && (nblk_bin <= NCHUNK_MAX) &&
                    ((n_edges / (nbuck > 0 ? nbuck : 1)) * 3 < CAP);

  if (fits) {
    // stage 1: bin counting sort ∥ logit chain (one launch, co-resident)
    int nblk1 = (n_nodes + 63) / 64;
    logit_bin_kernel<<<nblk_bin + nblk1, 256, 0, stream>>>(
        Nm, W1, w2, explog, nbf, n_nodes, src, dst, binout, dir, n_edges,
        nbuck, nblk_bin);

    // stage 2: per-bucket merge
    merge_kernel<<<nbuck, 256, 0, stream>>>(binout, dir, sorted, offsets,
                                            ends, n_nodes, nbuck, nblk_bin);

    // stage 3: accumulation (wave per node, lane-split 16B gathers)
    int ablk = (n_nodes + 3) / 4;
    accum_sorted_kernel<<<ablk, 256, 0, stream>>>(
        offsets, ends, sorted, explog, nbf, out, n_nodes);
  } else {
    // fallback: scalar logit + R1 atomic path
    float* logit = explog;
    float* denom = denomF;
    hipMemsetAsync(logit, 0, (size_t)n_pad * sizeof(float), stream);
    hipMemsetAsync(denom, 0, (size_t)n_pad * sizeof(float), stream);
    hipMemsetAsync(out, 0, (size_t)out_size * sizeof(float), stream);
    int nblk1 = (n_nodes + NPB - 1) / NPB;
    logit_kernel<<<nblk1, 256, 0, stream>>>(Nm, W1, w2, logit, n_nodes);
    int eblk = (n_edges + 255) / 256;
    denom_kernel<<<eblk, 256, 0, stream>>>(src, dst, logit, denom, n_edges);
    int nblk3 = (n_edges + 3) / 4;
    scatter_kernel<<<nblk3, 256, 0, stream>>>(src, dst, logit, denom, Nm, out,
                                              n_edges);
  }
}

// Round 13
// 67.463 us; speedup vs baseline: 1.8297x; 1.2058x over previous
//
#include <hip/hip_runtime.h>
#include <hip/hip_bf16.h>

#define D 128
#define NPB 16           // nodes per block in fallback logit kernel
#define CHUNK 3584       // edges per bin block (14KB ebuf; 224 blocks co-resident)
#define BKN 64           // dst nodes per bucket
#define MAXBUCK 1024     // max buckets
#define NCHUNK_MAX 256   // max bin chunks supported by merge
#define CAP 4096         // per-bucket window & merge LDS buffer (avg ~1024)

typedef __attribute__((ext_vector_type(8))) short bf16x8;
typedef __attribute__((ext_vector_type(4))) float f32x4;

__device__ __forceinline__ unsigned short f2bf_rne(float f) {
  unsigned u = __float_as_uint(f);
  unsigned r = (u + 0x7FFFu + ((u >> 16) & 1u)) >> 16;
  return (unsigned short)r;
}

__device__ __forceinline__ float fast_tanh(float x) {
  float e = __expf(2.0f * x);
  return 1.0f - 2.0f / (e + 1.0f);
}

// truncation-hi split: hi = top 16 bits (exact float hf), lo = rne(x - hf).
// hi+lo represents x to ~2^-17 rel; cheaper than double-RNE split.
__device__ __forceinline__ void split8(const float* __restrict__ p,
                                       bf16x8& hv, bf16x8& lv) {
  float4 a = *(const float4*)p;
  float4 b = *(const float4*)(p + 4);
  float xs[8] = {a.x, a.y, a.z, a.w, b.x, b.y, b.z, b.w};
#pragma unroll
  for (int i = 0; i < 8; ++i) {
    unsigned u = __float_as_uint(xs[i]);
    hv[i] = (short)(u >> 16);
    float r = xs[i] - __uint_as_float(u & 0xFFFF0000u);
    lv[i] = (short)f2bf_rne(r);
  }
}

struct SMLogit {
  unsigned short lhi[64 * 128];
  unsigned short llo[64 * 128];
  float part[4][64];
};
struct SMBin {
  unsigned cnt[MAXBUCK];
  unsigned cur[MAXBUCK];
  unsigned ebuf[CHUNK];
  int sdata[256];
};
union SMU {
  SMLogit lg;
  SMBin bn;
};

// ---------------------------------------------------------------------------
// Combined kernel (R11-verified structure), bin-first, fully co-resident.
// ---------------------------------------------------------------------------
__global__ __launch_bounds__(256, 2) void logit_bin_kernel(
    const float* __restrict__ Nm, const float* __restrict__ W1,
    const float* __restrict__ w2, float* __restrict__ explog,
    unsigned short* __restrict__ nbf, int n_nodes,
    const int* __restrict__ src, const int* __restrict__ dst,
    unsigned* __restrict__ binout, unsigned short* __restrict__ dir,
    int n_edges, int nbuck, int nblk_bin) {
  __shared__ SMU sm;
  const int tid = threadIdx.x;

  if ((int)blockIdx.x < nblk_bin) {
    // ================= bin role =================
    const int blk = (int)blockIdx.x;
    const int ebase = blk * CHUNK;
    const int chunkN = min(CHUNK, n_edges - ebase);

    for (int i = tid; i < MAXBUCK; i += 256) sm.bn.cnt[i] = 0;
    __syncthreads();

    for (int i = tid; i < chunkN; i += 256) {
      int d = dst[ebase + i];
      atomicAdd(&sm.bn.cnt[d >> 6], 1u);
    }
    __syncthreads();

    int t4 = tid * 4;
    int c0 = sm.bn.cnt[t4], c1 = sm.bn.cnt[t4 + 1];
    int c2 = sm.bn.cnt[t4 + 2], c3 = sm.bn.cnt[t4 + 3];
    int s = c0 + c1 + c2 + c3;
    sm.bn.sdata[tid] = s;
    __syncthreads();
    for (int d = 1; d < 256; d <<= 1) {
      int v = (tid >= d) ? sm.bn.sdata[tid - d] : 0;
      __syncthreads();
      sm.bn.sdata[tid] += v;
      __syncthreads();
    }
    int tb = sm.bn.sdata[tid] - s;
    sm.bn.cur[t4] = tb;
    sm.bn.cur[t4 + 1] = tb + c0;
    sm.bn.cur[t4 + 2] = tb + c0 + c1;
    sm.bn.cur[t4 + 3] = tb + c0 + c1 + c2;
    __syncthreads();

    size_t dbase = (size_t)blk * (nbuck + 1);
    for (int k = tid; k < nbuck; k += 256)
      dir[dbase + k] = (unsigned short)sm.bn.cur[k];
    if (tid == 0) dir[dbase + nbuck] = (unsigned short)chunkN;
    __syncthreads();

    for (int i = tid; i < chunkN; i += 256) {
      int d = dst[ebase + i];
      int sv = src[ebase + i];
      unsigned slot = atomicAdd(&sm.bn.cur[d >> 6], 1u);
      sm.bn.ebuf[slot] = (unsigned)sv | ((unsigned)(d & 63) << 16);
    }
    __syncthreads();

    for (int i = tid; i < chunkN; i += 256) binout[ebase + i] = sm.bn.ebuf[i];
  } else {
    // ================= logit role =================
    const int w = tid >> 6;
    const int l = tid & 63;
    const int lg = l >> 4;
    const int ln = l & 15;
    const int base = ((int)blockIdx.x - nblk_bin) * 64;

    bf16x8 Bh[2][4], Bl[2][4];
#pragma unroll
    for (int ntl = 0; ntl < 2; ++ntl) {
      int n = (w * 2 + ntl) * 16 + ln;
#pragma unroll
      for (int kt = 0; kt < 4; ++kt) {
        int k = kt * 32 + lg * 8;
        split8(W1 + n * 128 + k, Bh[ntl][kt], Bl[ntl][kt]);
      }
    }

#pragma unroll
    for (int i = 0; i < 8; ++i) {
      int flat = tid + i * 256;
      int row = flat >> 5;
      int c4 = flat & 31;
      int grow = base + row;
      if (grow >= n_nodes) grow = n_nodes - 1;
      float4 v = *(const float4*)(Nm + (size_t)grow * D + c4 * 4);
      unsigned ux = __float_as_uint(v.x), uy = __float_as_uint(v.y);
      unsigned uz = __float_as_uint(v.z), uw = __float_as_uint(v.w);
      unsigned short h0 = (unsigned short)(ux >> 16);
      unsigned short h1 = (unsigned short)(uy >> 16);
      unsigned short h2 = (unsigned short)(uz >> 16);
      unsigned short h3 = (unsigned short)(uw >> 16);
      unsigned short o0 = f2bf_rne(v.x - __uint_as_float(ux & 0xFFFF0000u));
      unsigned short o1 = f2bf_rne(v.y - __uint_as_float(uy & 0xFFFF0000u));
      unsigned short o2 = f2bf_rne(v.z - __uint_as_float(uz & 0xFFFF0000u));
      unsigned short o3 = f2bf_rne(v.w - __uint_as_float(uw & 0xFFFF0000u));
      int boff = (c4 * 8) ^ ((row & 7) << 4);
      *(ushort4*)((char*)sm.lg.lhi + row * 256 + boff) =
          make_ushort4(h0, h1, h2, h3);
      *(ushort4*)((char*)sm.lg.llo + row * 256 + boff) =
          make_ushort4(o0, o1, o2, o3);
      *(ushort4*)(nbf + (size_t)grow * D + c4 * 4) =
          make_ushort4(h0, h1, h2, h3);
    }
    __syncthreads();

    f32x4 acc[4][2];
#pragma unroll
    for (int mt = 0; mt < 4; ++mt)
#pragma unroll
      for (int ntl = 0; ntl < 2; ++ntl)
        acc[mt][ntl] = (f32x4){0.f, 0.f, 0.f, 0.f};

#pragma unroll
    for (int mt = 0; mt < 4; ++mt) {
      int row = mt * 16 + ln;
      bf16x8 Ah[4], Al[4];
#pragma unroll
      for (int kt = 0; kt < 4; ++kt) {
        int boff = (kt * 64 + lg * 16) ^ ((row & 7) << 4);
        Ah[kt] = *(const bf16x8*)((const char*)sm.lg.lhi + row * 256 + boff);
        Al[kt] = *(const bf16x8*)((const char*)sm.lg.llo + row * 256 + boff);
      }
#pragma unroll
      for (int ntl = 0; ntl < 2; ++ntl) {
#pragma unroll
        for (int kt = 0; kt < 4; ++kt) {
          acc[mt][ntl] = __builtin_amdgcn_mfma_f32_16x16x32_bf16(
              Ah[kt], Bh[ntl][kt], acc[mt][ntl], 0, 0, 0);
          acc[mt][ntl] = __builtin_amdgcn_mfma_f32_16x16x32_bf16(
              Ah[kt], Bl[ntl][kt], acc[mt][ntl], 0, 0, 0);
          acc[mt][ntl] = __builtin_amdgcn_mfma_f32_16x16x32_bf16(
              Al[kt], Bh[ntl][kt], acc[mt][ntl], 0, 0, 0);
        }
      }
    }

    float w2a = w2[(w * 2 + 0) * 16 + ln];
    float w2b = w2[(w * 2 + 1) * 16 + ln];
#pragma unroll
    for (int mt = 0; mt < 4; ++mt) {
      float s0 =
          fast_tanh(acc[mt][0][0]) * w2a + fast_tanh(acc[mt][1][0]) * w2b;
      float s1 =
          fast_tanh(acc[mt][0][1]) * w2a + fast_tanh(acc[mt][1][1]) * w2b;
      float s2 =
          fast_tanh(acc[mt][0][2]) * w2a + fast_tanh(acc[mt][1][2]) * w2b;
      float s3 =
          fast_tanh(acc[mt][0][3]) * w2a + fast_tanh(acc[mt][1][3]) * w2b;
#pragma unroll
      for (int mask = 1; mask < 16; mask <<= 1) {
        s0 += __shfl_xor(s0, mask);
        s1 += __shfl_xor(s1, mask);
        s2 += __shfl_xor(s2, mask);
        s3 += __shfl_xor(s3, mask);
      }
      if (ln < 4) {
        float sv = (ln == 0) ? s0 : (ln == 1) ? s1 : (ln == 2) ? s2 : s3;
        sm.lg.part[w][mt * 16 + lg * 4 + ln] = sv;
      }
    }
    __syncthreads();
    if (tid < 64) {
      int node = base + tid;
      if (node < n_nodes) {
        float t = sm.lg.part[0][tid] + sm.lg.part[1][tid] +
                  sm.lg.part[2][tid] + sm.lg.part[3][tid];
        explog[node] = expf(t);
      }
    }
  }
}

// ---------------------------------------------------------------------------
// Merge: one block per bucket -> private window. Parallel run-gather
// (8 lanes/run, 32 runs in flight); 4-elem/lane wave scan (256 chunks).
// ---------------------------------------------------------------------------
__global__ __launch_bounds__(256) void merge_kernel(
    const unsigned* __restrict__ binout, const unsigned short* __restrict__ dir,
    unsigned* __restrict__ sorted, int* __restrict__ offsets,
    int* __restrict__ ends, int n_nodes, int nbuck, int nblk_bin) {
  __shared__ unsigned ebuf[CAP];
  __shared__ int lens[NCHUNK_MAX], cstart[NCHUNK_MAX], ls0[NCHUNK_MAX];
  __shared__ int cnt[BKN], nstart[BKN], cur[BKN];
  __shared__ int total;
  const int tid = threadIdx.x;
  const int w = tid >> 6, lane = tid & 63;
  const int bk = blockIdx.x;
  const int node0 = bk * BKN;
  const int base = bk * CAP;

  if (tid < nblk_bin) {
    size_t dbase = (size_t)tid * (nbuck + 1);
    int s0 = dir[dbase + bk];
    int s1 = dir[dbase + bk + 1];
    ls0[tid] = s0;
    lens[tid] = s1 - s0;
  }
  if (tid < BKN) cnt[tid] = 0;
  __syncthreads();

  // chunk exclusive scan (wave 0, 4 elems/lane, shfl_up)
  if (w == 0) {
    int l0 = lane * 4;
    int a = (l0 + 0 < nblk_bin) ? lens[l0 + 0] : 0;
    int b = (l0 + 1 < nblk_bin) ? lens[l0 + 1] : 0;
    int c = (l0 + 2 < nblk_bin) ? lens[l0 + 2] : 0;
    int d = (l0 + 3 < nblk_bin) ? lens[l0 + 3] : 0;
    int sv = a + b + c + d;
    int inc = sv;
#pragma unroll
    for (int off = 1; off < 64; off <<= 1) {
      int t = __shfl_up(inc, off);
      if (lane >= off) inc += t;
    }
    int ex = inc - sv;
    if (l0 + 0 < nblk_bin) cstart[l0 + 0] = ex;
    if (l0 + 1 < nblk_bin) cstart[l0 + 1] = ex + a;
    if (l0 + 2 < nblk_bin) cstart[l0 + 2] = ex + a + b;
    if (l0 + 3 < nblk_bin) cstart[l0 + 3] = ex + a + b + c;
    if (lane == 63) total = (inc > CAP) ? CAP : inc;
  }
  __syncthreads();
  const int tot = total;

  // gather runs: 8 lanes per run, 32 runs in flight block-wide
  {
    const int rg = lane >> 3;  // run group 0..7 within wave
    const int li = lane & 7;   // lane within run
    for (int r = w * 8 + rg; r < nblk_bin; r += 32) {
      int len = lens[r], cs = cstart[r];
      if (cs >= CAP) continue;
      if (cs + len > CAP) len = CAP - cs;
      const unsigned* g = binout + (size_t)r * CHUNK + ls0[r];
      for (int i = li; i < len; i += 8) ebuf[cs + i] = g[i];
    }
  }
  __syncthreads();

  // count per node
  for (int i = tid; i < tot; i += 256) atomicAdd(&cnt[ebuf[i] >> 16], 1);
  __syncthreads();

  // node exclusive scan (wave 0, 1 elem/lane)
  if (w == 0) {
    int c = cnt[lane];
    int inc = c;
#pragma unroll
    for (int off = 1; off < 64; off <<= 1) {
      int t = __shfl_up(inc, off);
      if (lane >= off) inc += t;
    }
    nstart[lane] = inc - c;
  }
  __syncthreads();

  if (tid < BKN) {
    cur[tid] = nstart[tid];
    int node = node0 + tid;
    if (node < n_nodes) {
      offsets[node] = base + nstart[tid];
      ends[node] = base + nstart[tid] + cnt[tid];
    }
  }
  __syncthreads();

  for (int i = tid; i < tot; i += 256) {
    unsigned p = ebuf[i];
    int pos = atomicAdd(&cur[p >> 16], 1);
    sorted[(size_t)base + pos] = p;
  }
}

// ---------------------------------------------------------------------------
// Accum (R12): wave per dst node, lane-split (eg=lane>>4 edge, fl=lane&15
// feature block); per 4 edges: 1 sorted + 1 explog dword + 1 nbf dwordx4.
// ---------------------------------------------------------------------------
__global__ __launch_bounds__(256) void accum_sorted_kernel(
    const int* __restrict__ offsets, const int* __restrict__ ends,
    const unsigned* __restrict__ sorted, const float* __restrict__ explog,
    const unsigned short* __restrict__ nbf, float* __restrict__ out,
    int n_nodes) {
  int node = (blockIdx.x * 256 + threadIdx.x) >> 6;
  int lane = threadIdx.x & 63;
  if (node >= n_nodes) return;
  const int eg = lane >> 4;
  const int fl = lane & 15;
  int beg = offsets[node], end = ends[node];
  int last = end - 1;
  float acc[8];
#pragma unroll
  for (int j = 0; j < 8; ++j) acc[j] = 0.f;
  float den = 0.f;

  for (int e = beg; e < end; e += 8) {
    int ea = e + eg;
    int eb = e + 4 + eg;
    int eca = (ea < last) ? ea : last;
    int ecb = (eb < last) ? eb : last;
    unsigned pa = sorted[eca];
    unsigned pb = sorted[ecb];
    int sa = pa & 0xFFFF, sb = pb & 0xFFFF;
    float xa = explog[sa];
    float xb = explog[sb];
    uint4 ua = *(const uint4*)(nbf + (size_t)sa * D + fl * 8);
    uint4 ub = *(const uint4*)(nbf + (size_t)sb * D + fl * 8);
    xa = (ea < end) ? xa : 0.f;
    xb = (eb < end) ? xb : 0.f;
    den += xa + xb;
    unsigned va[4] = {ua.x, ua.y, ua.z, ua.w};
    unsigned vb[4] = {ub.x, ub.y, ub.z, ub.w};
#pragma unroll
    for (int j = 0; j < 4; ++j) {
      acc[2 * j] += xa * __uint_as_float(va[j] << 16) +
                    xb * __uint_as_float(vb[j] << 16);
      acc[2 * j + 1] += xa * __uint_as_float(va[j] & 0xFFFF0000u) +
                        xb * __uint_as_float(vb[j] & 0xFFFF0000u);
    }
  }

#pragma unroll
  for (int j = 0; j < 8; ++j) {
    acc[j] += __shfl_xor(acc[j], 16);
    acc[j] += __shfl_xor(acc[j], 32);
  }
  den += __shfl_xor(den, 16);
  den += __shfl_xor(den, 32);

  if (eg == 0) {
    float inv = (end > beg) ? 1.0f / den : 0.f;
    float4 o0 = make_float4(acc[0] * inv, acc[1] * inv, acc[2] * inv,
                            acc[3] * inv);
    float4 o1 = make_float4(acc[4] * inv, acc[5] * inv, acc[6] * inv,
                            acc[7] * inv);
    float* orow = out + (size_t)node * D + fl * 8;
    *(float4*)orow = o0;
    *(float4*)(orow + 4) = o1;
  }
}

// ---------------------------------------------------------------------------
// Fallback path: scalar logit + per-edge atomics (R1, verified)
// ---------------------------------------------------------------------------
__global__ __launch_bounds__(256) void logit_kernel(
    const float* __restrict__ Nm, const float* __restrict__ W1,
    const float* __restrict__ w2, float* __restrict__ logit, int n_nodes) {
  __shared__ float w1t[32 * 129];
  const int tid = threadIdx.x;
  const int j = tid & 127;
  const int half = tid >> 7;
  const int base = blockIdx.x * NPB;
  float acc[8];
#pragma unroll
  for (int g = 0; g < 8; ++g) acc[g] = 0.f;
  for (int c = 0; c < 4; ++c) {
    __syncthreads();
    for (int idx = tid; idx < 128 * 32; idx += 256) {
      int kl = idx & 31, jj = idx >> 5;
      w1t[kl * 129 + jj] = W1[jj * 128 + c * 32 + kl];
    }
    __syncthreads();
#pragma unroll
    for (int g = 0; g < 8; ++g) {
      int node = base + g * 2 + half;
      if (node < n_nodes) {
        const float4* nrow =
            reinterpret_cast<const float4*>(Nm + (size_t)node * D + c * 32);
        float a = acc[g];
#pragma unroll
        for (int k4 = 0; k4 < 8; ++k4) {
          float4 nv = nrow[k4];
          int kl = k4 * 4;
          a += nv.x * w1t[(kl + 0) * 129 + j];
          a += nv.y * w1t[(kl + 1) * 129 + j];
          a += nv.z * w1t[(kl + 2) * 129 + j];
          a += nv.w * w1t[(kl + 3) * 129 + j];
        }
        acc[g] = a;
      }
    }
  }
  const float w2j = w2[j];
#pragma unroll
  for (int g = 0; g < 8; ++g) {
    int node = base + g * 2 + half;
    float t = tanhf(acc[g]) * w2j;
#pragma unroll
    for (int off = 32; off; off >>= 1) t += __shfl_down(t, off);
    if ((tid & 63) == 0 && node < n_nodes) atomicAdd(&logit[node], t);
  }
}

__global__ __launch_bounds__(256) void denom_kernel(
    const int* __restrict__ src, const int* __restrict__ dst,
    const float* __restrict__ logit, float* __restrict__ denom, int n_edges) {
  int e = blockIdx.x * 256 + threadIdx.x;
  if (e < n_edges) {
    float ex = expf(logit[src[e]]);
    atomicAdd(&denom[dst[e]], ex);
  }
}

__global__ __launch_bounds__(256) void scatter_kernel(
    const int* __restrict__ src, const int* __restrict__ dst,
    const float* __restrict__ logit, const float* __restrict__ denom,
    const float* __restrict__ Nm, float* __restrict__ out, int n_edges) {
  int wave = (blockIdx.x * 256 + threadIdx.x) >> 6;
  int lane = threadIdx.x & 63;
  if (wave >= n_edges) return;
  int s = src[wave];
  int d = dst[wave];
  float a = expf(logit[s]) / denom[d];
  float v0 = Nm[(size_t)s * D + lane];
  float v1 = Nm[(size_t)s * D + 64 + lane];
  atomicAdd(&out[(size_t)d * D + lane], a * v0);
  atomicAdd(&out[(size_t)d * D + 64 + lane], a * v1);
}

static inline char* align_up(char* p, size_t a) {
  return (char*)(((uintptr_t)p + a - 1) & ~(uintptr_t)(a - 1));
}

extern "C" void kernel_launch(void* const* d_in, const int* in_sizes, int n_in,
                              void* d_out, int out_size, void* d_ws,
                              size_t ws_size, hipStream_t stream) {
  const float* Nm  = (const float*)d_in[0];
  const float* W1  = (const float*)d_in[1];
  const float* w2  = (const float*)d_in[2];
  const int*   src = (const int*)d_in[3];
  const int*   dst = (const int*)d_in[4];
  float* out = (float*)d_out;

  const int n_nodes = in_sizes[0] / D;
  const int n_edges = in_sizes[3];
  const int n_pad = (n_nodes + 63) & ~63;
  const int nbuck = (n_nodes + BKN - 1) / BKN;
  const int nblk_bin = (n_edges + CHUNK - 1) / CHUNK;

  // carve workspace
  char* p = (char*)d_ws;
  float* explog = (float*)p;     p = align_up(p + (size_t)n_pad * 4, 256);
  float* denomF = (float*)p;     p = align_up(p + (size_t)n_pad * 4, 256);
  unsigned short* nbf = (unsigned short*)p;
  p = align_up(p + (size_t)n_nodes * D * 2, 256);
  unsigned* binout = (unsigned*)p;
  p = align_up(p + (size_t)nblk_bin * CHUNK * 4, 256);
  unsigned short* dir = (unsigned short*)p;
  p = align_up(p + (size_t)nblk_bin * (nbuck + 1) * 2, 256);
  unsigned* sorted = (unsigned*)p;
  p = align_up(p + (size_t)nbuck * CAP * 4, 256);
  int* offsets = (int*)p;        p = align_up(p + (size_t)n_pad * 4, 256);
  int* ends    = (int*)p;        p = align_up(p + (size_t)n_pad * 4, 256);
  size_t needed = (size_t)(p - (char*)d_ws);

  const bool fits = (ws_size >= needed) && (n_nodes <= 65535) &&
                    (nbuck <= MAXBUCK) && (nblk_bin <= NCHUNK_MAX) &&
                    ((n_edges / (nbuck > 0 ? nbuck : 1)) * 3 < CAP);

  if (fits) {
    // stage 1: bin counting sort ∥ logit chain (one launch, co-resident)
    int nblk1 = (n_nodes + 63) / 64;
    logit_bin_kernel<<<nblk_bin + nblk1, 256, 0, stream>>>(
        Nm, W1, w2, explog, nbf, n_nodes, src, dst, binout, dir, n_edges,
        nbuck, nblk_bin);

    // stage 2: per-bucket merge
    merge_kernel<<<nbuck, 256, 0, stream>>>(binout, dir, sorted, offsets,
                                            ends, n_nodes, nbuck, nblk_bin);

    // stage 3: accumulation (wave per node, lane-split 16B gathers)
    int ablk = (n_nodes + 3) / 4;
    accum_sorted_kernel<<<ablk, 256, 0, stream>>>(
        offsets, ends, sorted, explog, nbf, out, n_nodes);
  } else {
    // fallback: scalar logit + R1 atomic path
    float* logit = explog;
    float* denom = denomF;
    hipMemsetAsync(logit, 0, (size_t)n_pad * sizeof(float), stream);
    hipMemsetAsync(denom, 0, (size_t)n_pad * sizeof(float), stream);
    hipMemsetAsync(out, 0, (size_t)out_size * sizeof(float), stream);
    int nblk1 = (n_nodes + NPB - 1) / NPB;
    logit_kernel<<<nblk1, 256, 0, stream>>>(Nm, W1, w2, logit, n_nodes);
    int eblk = (n_edges + 255) / 256;
    denom_kernel<<<eblk, 256, 0, stream>>>(src, dst, logit, denom, n_edges);
    int nblk3 = (n_edges + 3) / 4;
    scatter_kernel<<<nblk3, 256, 0, stream>>>(src, dst, logit, denom, Nm, out,
                                              n_edges);
  }
}

// Round 14
// 66.792 us; speedup vs baseline: 1.8480x; 1.0100x over previous
//
#include <hip/hip_runtime.h>
#include <hip/hip_bf16.h>

#define D 128
#define NPB 16           // nodes per block in fallback logit kernel
#define CHUNK 3584       // edges per bin block (14KB ebuf; 224 blocks co-resident)
#define BKN 64           // dst nodes per bucket
#define MAXBUCK 1024     // max buckets
#define NCHUNK_MAX 256   // max bin chunks supported by merge
#define CAP 4096         // per-bucket window & merge LDS buffer (avg ~1024)

typedef __attribute__((ext_vector_type(8))) short bf16x8;
typedef __attribute__((ext_vector_type(4))) float f32x4;

__device__ __forceinline__ unsigned short f2bf_rne(float f) {
  unsigned u = __float_as_uint(f);
  unsigned r = (u + 0x7FFFu + ((u >> 16) & 1u)) >> 16;
  return (unsigned short)r;
}

__device__ __forceinline__ float fast_tanh(float x) {
  float e = __expf(2.0f * x);
  return 1.0f - 2.0f / (e + 1.0f);
}

// truncation-hi split: hi = top 16 bits (exact float hf), lo = rne(x - hf).
__device__ __forceinline__ void split8(const float* __restrict__ p,
                                       bf16x8& hv, bf16x8& lv) {
  float4 a = *(const float4*)p;
  float4 b = *(const float4*)(p + 4);
  float xs[8] = {a.x, a.y, a.z, a.w, b.x, b.y, b.z, b.w};
#pragma unroll
  for (int i = 0; i < 8; ++i) {
    unsigned u = __float_as_uint(xs[i]);
    hv[i] = (short)(u >> 16);
    float r = xs[i] - __uint_as_float(u & 0xFFFF0000u);
    lv[i] = (short)f2bf_rne(r);
  }
}

struct SMLogit {
  unsigned short lhi[64 * 128];
  unsigned short llo[64 * 128];
  float part[4][64];
};
struct SMBin {
  unsigned cnt[MAXBUCK];
  unsigned cur[MAXBUCK];
  unsigned ebuf[CHUNK];
  int sdata[256];
};
union SMU {
  SMLogit lg;
  SMBin bn;
};

// ---------------------------------------------------------------------------
// Combined kernel (R11/R13-verified), bin-first, fully co-resident.
// ---------------------------------------------------------------------------
__global__ __launch_bounds__(256, 2) void logit_bin_kernel(
    const float* __restrict__ Nm, const float* __restrict__ W1,
    const float* __restrict__ w2, float* __restrict__ explog,
    unsigned short* __restrict__ nbf, int n_nodes,
    const int* __restrict__ src, const int* __restrict__ dst,
    unsigned* __restrict__ binout, unsigned short* __restrict__ dir,
    int n_edges, int nbuck, int nblk_bin) {
  __shared__ SMU sm;
  const int tid = threadIdx.x;

  if ((int)blockIdx.x < nblk_bin) {
    // ================= bin role =================
    const int blk = (int)blockIdx.x;
    const int ebase = blk * CHUNK;
    const int chunkN = min(CHUNK, n_edges - ebase);

    for (int i = tid; i < MAXBUCK; i += 256) sm.bn.cnt[i] = 0;
    __syncthreads();

    for (int i = tid; i < chunkN; i += 256) {
      int d = dst[ebase + i];
      atomicAdd(&sm.bn.cnt[d >> 6], 1u);
    }
    __syncthreads();

    int t4 = tid * 4;
    int c0 = sm.bn.cnt[t4], c1 = sm.bn.cnt[t4 + 1];
    int c2 = sm.bn.cnt[t4 + 2], c3 = sm.bn.cnt[t4 + 3];
    int s = c0 + c1 + c2 + c3;
    sm.bn.sdata[tid] = s;
    __syncthreads();
    for (int d = 1; d < 256; d <<= 1) {
      int v = (tid >= d) ? sm.bn.sdata[tid - d] : 0;
      __syncthreads();
      sm.bn.sdata[tid] += v;
      __syncthreads();
    }
    int tb = sm.bn.sdata[tid] - s;
    sm.bn.cur[t4] = tb;
    sm.bn.cur[t4 + 1] = tb + c0;
    sm.bn.cur[t4 + 2] = tb + c0 + c1;
    sm.bn.cur[t4 + 3] = tb + c0 + c1 + c2;
    __syncthreads();

    size_t dbase = (size_t)blk * (nbuck + 1);
    for (int k = tid; k < nbuck; k += 256)
      dir[dbase + k] = (unsigned short)sm.bn.cur[k];
    if (tid == 0) dir[dbase + nbuck] = (unsigned short)chunkN;
    __syncthreads();

    for (int i = tid; i < chunkN; i += 256) {
      int d = dst[ebase + i];
      int sv = src[ebase + i];
      unsigned slot = atomicAdd(&sm.bn.cur[d >> 6], 1u);
      sm.bn.ebuf[slot] = (unsigned)sv | ((unsigned)(d & 63) << 16);
    }
    __syncthreads();

    for (int i = tid; i < chunkN; i += 256) binout[ebase + i] = sm.bn.ebuf[i];
  } else {
    // ================= logit role =================
    const int w = tid >> 6;
    const int l = tid & 63;
    const int lg = l >> 4;
    const int ln = l & 15;
    const int base = ((int)blockIdx.x - nblk_bin) * 64;

    bf16x8 Bh[2][4], Bl[2][4];
#pragma unroll
    for (int ntl = 0; ntl < 2; ++ntl) {
      int n = (w * 2 + ntl) * 16 + ln;
#pragma unroll
      for (int kt = 0; kt < 4; ++kt) {
        int k = kt * 32 + lg * 8;
        split8(W1 + n * 128 + k, Bh[ntl][kt], Bl[ntl][kt]);
      }
    }

#pragma unroll
    for (int i = 0; i < 8; ++i) {
      int flat = tid + i * 256;
      int row = flat >> 5;
      int c4 = flat & 31;
      int grow = base + row;
      if (grow >= n_nodes) grow = n_nodes - 1;
      float4 v = *(const float4*)(Nm + (size_t)grow * D + c4 * 4);
      unsigned ux = __float_as_uint(v.x), uy = __float_as_uint(v.y);
      unsigned uz = __float_as_uint(v.z), uw = __float_as_uint(v.w);
      unsigned short h0 = (unsigned short)(ux >> 16);
      unsigned short h1 = (unsigned short)(uy >> 16);
      unsigned short h2 = (unsigned short)(uz >> 16);
      unsigned short h3 = (unsigned short)(uw >> 16);
      unsigned short o0 = f2bf_rne(v.x - __uint_as_float(ux & 0xFFFF0000u));
      unsigned short o1 = f2bf_rne(v.y - __uint_as_float(uy & 0xFFFF0000u));
      unsigned short o2 = f2bf_rne(v.z - __uint_as_float(uz & 0xFFFF0000u));
      unsigned short o3 = f2bf_rne(v.w - __uint_as_float(uw & 0xFFFF0000u));
      int boff = (c4 * 8) ^ ((row & 7) << 4);
      *(ushort4*)((char*)sm.lg.lhi + row * 256 + boff) =
          make_ushort4(h0, h1, h2, h3);
      *(ushort4*)((char*)sm.lg.llo + row * 256 + boff) =
          make_ushort4(o0, o1, o2, o3);
      *(ushort4*)(nbf + (size_t)grow * D + c4 * 4) =
          make_ushort4(h0, h1, h2, h3);
    }
    __syncthreads();

    f32x4 acc[4][2];
#pragma unroll
    for (int mt = 0; mt < 4; ++mt)
#pragma unroll
      for (int ntl = 0; ntl < 2; ++ntl)
        acc[mt][ntl] = (f32x4){0.f, 0.f, 0.f, 0.f};

#pragma unroll
    for (int mt = 0; mt < 4; ++mt) {
      int row = mt * 16 + ln;
      bf16x8 Ah[4], Al[4];
#pragma unroll
      for (int kt = 0; kt < 4; ++kt) {
        int boff = (kt * 64 + lg * 16) ^ ((row & 7) << 4);
        Ah[kt] = *(const bf16x8*)((const char*)sm.lg.lhi + row * 256 + boff);
        Al[kt] = *(const bf16x8*)((const char*)sm.lg.llo + row * 256 + boff);
      }
#pragma unroll
      for (int ntl = 0; ntl < 2; ++ntl) {
#pragma unroll
        for (int kt = 0; kt < 4; ++kt) {
          acc[mt][ntl] = __builtin_amdgcn_mfma_f32_16x16x32_bf16(
              Ah[kt], Bh[ntl][kt], acc[mt][ntl], 0, 0, 0);
          acc[mt][ntl] = __builtin_amdgcn_mfma_f32_16x16x32_bf16(
              Ah[kt], Bl[ntl][kt], acc[mt][ntl], 0, 0, 0);
          acc[mt][ntl] = __builtin_amdgcn_mfma_f32_16x16x32_bf16(
              Al[kt], Bh[ntl][kt], acc[mt][ntl], 0, 0, 0);
        }
      }
    }

    float w2a = w2[(w * 2 + 0) * 16 + ln];
    float w2b = w2[(w * 2 + 1) * 16 + ln];
#pragma unroll
    for (int mt = 0; mt < 4; ++mt) {
      float s0 =
          fast_tanh(acc[mt][0][0]) * w2a + fast_tanh(acc[mt][1][0]) * w2b;
      float s1 =
          fast_tanh(acc[mt][0][1]) * w2a + fast_tanh(acc[mt][1][1]) * w2b;
      float s2 =
          fast_tanh(acc[mt][0][2]) * w2a + fast_tanh(acc[mt][1][2]) * w2b;
      float s3 =
          fast_tanh(acc[mt][0][3]) * w2a + fast_tanh(acc[mt][1][3]) * w2b;
#pragma unroll
      for (int mask = 1; mask < 16; mask <<= 1) {
        s0 += __shfl_xor(s0, mask);
        s1 += __shfl_xor(s1, mask);
        s2 += __shfl_xor(s2, mask);
        s3 += __shfl_xor(s3, mask);
      }
      if (ln < 4) {
        float sv = (ln == 0) ? s0 : (ln == 1) ? s1 : (ln == 2) ? s2 : s3;
        sm.lg.part[w][mt * 16 + lg * 4 + ln] = sv;
      }
    }
    __syncthreads();
    if (tid < 64) {
      int node = base + tid;
      if (node < n_nodes) {
        float t = sm.lg.part[0][tid] + sm.lg.part[1][tid] +
                  sm.lg.part[2][tid] + sm.lg.part[3][tid];
        explog[node] = expf(t);
      }
    }
  }
}

// ---------------------------------------------------------------------------
// Merge (R13-verified): parallel run-gather, wave scans, private windows.
// ---------------------------------------------------------------------------
__global__ __launch_bounds__(256) void merge_kernel(
    const unsigned* __restrict__ binout, const unsigned short* __restrict__ dir,
    unsigned* __restrict__ sorted, int* __restrict__ offsets,
    int* __restrict__ ends, int n_nodes, int nbuck, int nblk_bin) {
  __shared__ unsigned ebuf[CAP];
  __shared__ int lens[NCHUNK_MAX], cstart[NCHUNK_MAX], ls0[NCHUNK_MAX];
  __shared__ int cnt[BKN], nstart[BKN], cur[BKN];
  __shared__ int total;
  const int tid = threadIdx.x;
  const int w = tid >> 6, lane = tid & 63;
  const int bk = blockIdx.x;
  const int node0 = bk * BKN;
  const int base = bk * CAP;

  if (tid < nblk_bin) {
    size_t dbase = (size_t)tid * (nbuck + 1);
    int s0 = dir[dbase + bk];
    int s1 = dir[dbase + bk + 1];
    ls0[tid] = s0;
    lens[tid] = s1 - s0;
  }
  if (tid < BKN) cnt[tid] = 0;
  __syncthreads();

  if (w == 0) {
    int l0 = lane * 4;
    int a = (l0 + 0 < nblk_bin) ? lens[l0 + 0] : 0;
    int b = (l0 + 1 < nblk_bin) ? lens[l0 + 1] : 0;
    int c = (l0 + 2 < nblk_bin) ? lens[l0 + 2] : 0;
    int d = (l0 + 3 < nblk_bin) ? lens[l0 + 3] : 0;
    int sv = a + b + c + d;
    int inc = sv;
#pragma unroll
    for (int off = 1; off < 64; off <<= 1) {
      int t = __shfl_up(inc, off);
      if (lane >= off) inc += t;
    }
    int ex = inc - sv;
    if (l0 + 0 < nblk_bin) cstart[l0 + 0] = ex;
    if (l0 + 1 < nblk_bin) cstart[l0 + 1] = ex + a;
    if (l0 + 2 < nblk_bin) cstart[l0 + 2] = ex + a + b;
    if (l0 + 3 < nblk_bin) cstart[l0 + 3] = ex + a + b + c;
    if (lane == 63) total = (inc > CAP) ? CAP : inc;
  }
  __syncthreads();
  const int tot = total;

  {
    const int rg = lane >> 3;
    const int li = lane & 7;
    for (int r = w * 8 + rg; r < nblk_bin; r += 32) {
      int len = lens[r], cs = cstart[r];
      if (cs >= CAP) continue;
      if (cs + len > CAP) len = CAP - cs;
      const unsigned* g = binout + (size_t)r * CHUNK + ls0[r];
      for (int i = li; i < len; i += 8) ebuf[cs + i] = g[i];
    }
  }
  __syncthreads();

  for (int i = tid; i < tot; i += 256) atomicAdd(&cnt[ebuf[i] >> 16], 1);
  __syncthreads();

  if (w == 0) {
    int c = cnt[lane];
    int inc = c;
#pragma unroll
    for (int off = 1; off < 64; off <<= 1) {
      int t = __shfl_up(inc, off);
      if (lane >= off) inc += t;
    }
    nstart[lane] = inc - c;
  }
  __syncthreads();

  if (tid < BKN) {
    cur[tid] = nstart[tid];
    int node = node0 + tid;
    if (node < n_nodes) {
      offsets[node] = base + nstart[tid];
      ends[node] = base + nstart[tid] + cnt[tid];
    }
  }
  __syncthreads();

  for (int i = tid; i < tot; i += 256) {
    unsigned p = ebuf[i];
    int pos = atomicAdd(&cur[p >> 16], 1);
    sorted[(size_t)base + pos] = p;
  }
}

// ---------------------------------------------------------------------------
// Accum: wave per node pair, lane-split (eg=lane>>4 edge slot, fl=lane&15
// feature block). 16 edges per iteration (4 clamped quads -> 4 uint4 + 4
// dword gathers in flight per lane). Edge-groups combined via shfl_xor.
// ---------------------------------------------------------------------------
__global__ __launch_bounds__(256) void accum_sorted_kernel(
    const int* __restrict__ offsets, const int* __restrict__ ends,
    const unsigned* __restrict__ sorted, const float* __restrict__ explog,
    const unsigned short* __restrict__ nbf, float* __restrict__ out,
    int n_nodes, int n_half) {
  int wv = (blockIdx.x * 256 + threadIdx.x) >> 6;
  int lane = threadIdx.x & 63;
  const int eg = lane >> 4;
  const int fl = lane & 15;

#pragma unroll
  for (int half = 0; half < 2; ++half) {
    int node = wv + half * n_half;
    if (node >= n_nodes) break;
    int beg = offsets[node], end = ends[node];
    int last = end - 1;
    float acc[8];
#pragma unroll
    for (int j = 0; j < 8; ++j) acc[j] = 0.f;
    float den = 0.f;

    for (int e = beg; e < end; e += 16) {
      int ei[4];
      unsigned pv[4];
      float xv[4];
      uint4 uv[4];
#pragma unroll
      for (int q = 0; q < 4; ++q) {
        int ee = e + q * 4 + eg;
        ei[q] = ee;
        int ec = (ee < last) ? ee : last;
        pv[q] = sorted[ec];
      }
#pragma unroll
      for (int q = 0; q < 4; ++q) {
        int sq = pv[q] & 0xFFFF;
        xv[q] = explog[sq];
        uv[q] = *(const uint4*)(nbf + (size_t)sq * D + fl * 8);
      }
#pragma unroll
      for (int q = 0; q < 4; ++q) {
        float xq = (ei[q] < end) ? xv[q] : 0.f;
        den += xq;
        unsigned v0 = uv[q].x, v1 = uv[q].y, v2 = uv[q].z, v3 = uv[q].w;
        acc[0] += xq * __uint_as_float(v0 << 16);
        acc[1] += xq * __uint_as_float(v0 & 0xFFFF0000u);
        acc[2] += xq * __uint_as_float(v1 << 16);
        acc[3] += xq * __uint_as_float(v1 & 0xFFFF0000u);
        acc[4] += xq * __uint_as_float(v2 << 16);
        acc[5] += xq * __uint_as_float(v2 & 0xFFFF0000u);
        acc[6] += xq * __uint_as_float(v3 << 16);
        acc[7] += xq * __uint_as_float(v3 & 0xFFFF0000u);
      }
    }

#pragma unroll
    for (int j = 0; j < 8; ++j) {
      acc[j] += __shfl_xor(acc[j], 16);
      acc[j] += __shfl_xor(acc[j], 32);
    }
    den += __shfl_xor(den, 16);
    den += __shfl_xor(den, 32);

    if (eg == 0) {
      float inv = (end > beg) ? 1.0f / den : 0.f;
      float4 o0 = make_float4(acc[0] * inv, acc[1] * inv, acc[2] * inv,
                              acc[3] * inv);
      float4 o1 = make_float4(acc[4] * inv, acc[5] * inv, acc[6] * inv,
                              acc[7] * inv);
      float* orow = out + (size_t)node * D + fl * 8;
      *(float4*)orow = o0;
      *(float4*)(orow + 4) = o1;
    }
  }
}

// ---------------------------------------------------------------------------
// Fallback path: scalar logit + per-edge atomics (R1, verified)
// ---------------------------------------------------------------------------
__global__ __launch_bounds__(256) void logit_kernel(
    const float* __restrict__ Nm, const float* __restrict__ W1,
    const float* __restrict__ w2, float* __restrict__ logit, int n_nodes) {
  __shared__ float w1t[32 * 129];
  const int tid = threadIdx.x;
  const int j = tid & 127;
  const int half = tid >> 7;
  const int base = blockIdx.x * NPB;
  float acc[8];
#pragma unroll
  for (int g = 0; g < 8; ++g) acc[g] = 0.f;
  for (int c = 0; c < 4; ++c) {
    __syncthreads();
    for (int idx = tid; idx < 128 * 32; idx += 256) {
      int kl = idx & 31, jj = idx >> 5;
      w1t[kl * 129 + jj] = W1[jj * 128 + c * 32 + kl];
    }
    __syncthreads();
#pragma unroll
    for (int g = 0; g < 8; ++g) {
      int node = base + g * 2 + half;
      if (node < n_nodes) {
        const float4* nrow =
            reinterpret_cast<const float4*>(Nm + (size_t)node * D + c * 32);
        float a = acc[g];
#pragma unroll
        for (int k4 = 0; k4 < 8; ++k4) {
          float4 nv = nrow[k4];
          int kl = k4 * 4;
          a += nv.x * w1t[(kl + 0) * 129 + j];
          a += nv.y * w1t[(kl + 1) * 129 + j];
          a += nv.z * w1t[(kl + 2) * 129 + j];
          a += nv.w * w1t[(kl + 3) * 129 + j];
        }
        acc[g] = a;
      }
    }
  }
  const float w2j = w2[j];
#pragma unroll
  for (int g = 0; g < 8; ++g) {
    int node = base + g * 2 + half;
    float t = tanhf(acc[g]) * w2j;
#pragma unroll
    for (int off = 32; off; off >>= 1) t += __shfl_down(t, off);
    if ((tid & 63) == 0 && node < n_nodes) atomicAdd(&logit[node], t);
  }
}

__global__ __launch_bounds__(256) void denom_kernel(
    const int* __restrict__ src, const int* __restrict__ dst,
    const float* __restrict__ logit, float* __restrict__ denom, int n_edges) {
  int e = blockIdx.x * 256 + threadIdx.x;
  if (e < n_edges) {
    float ex = expf(logit[src[e]]);
    atomicAdd(&denom[dst[e]], ex);
  }
}

__global__ __launch_bounds__(256) void scatter_kernel(
    const int* __restrict__ src, const int* __restrict__ dst,
    const float* __restrict__ logit, const float* __restrict__ denom,
    const float* __restrict__ Nm, float* __restrict__ out, int n_edges) {
  int wave = (blockIdx.x * 256 + threadIdx.x) >> 6;
  int lane = threadIdx.x & 63;
  if (wave >= n_edges) return;
  int s = src[wave];
  int d = dst[wave];
  float a = expf(logit[s]) / denom[d];
  float v0 = Nm[(size_t)s * D + lane];
  float v1 = Nm[(size_t)s * D + 64 + lane];
  atomicAdd(&out[(size_t)d * D + lane], a * v0);
  atomicAdd(&out[(size_t)d * D + 64 + lane], a * v1);
}

static inline char* align_up(char* p, size_t a) {
  return (char*)(((uintptr_t)p + a - 1) & ~(uintptr_t)(a - 1));
}

extern "C" void kernel_launch(void* const* d_in, const int* in_sizes, int n_in,
                              void* d_out, int out_size, void* d_ws,
                              size_t ws_size, hipStream_t stream) {
  const float* Nm  = (const float*)d_in[0];
  const float* W1  = (const float*)d_in[1];
  const float* w2  = (const float*)d_in[2];
  const int*   src = (const int*)d_in[3];
  const int*   dst = (const int*)d_in[4];
  float* out = (float*)d_out;

  const int n_nodes = in_sizes[0] / D;
  const int n_edges = in_sizes[3];
  const int n_pad = (n_nodes + 63) & ~63;
  const int nbuck = (n_nodes + BKN - 1) / BKN;
  const int nblk_bin = (n_edges + CHUNK - 1) / CHUNK;

  // carve workspace
  char* p = (char*)d_ws;
  float* explog = (float*)p;     p = align_up(p + (size_t)n_pad * 4, 256);
  float* denomF = (float*)p;     p = align_up(p + (size_t)n_pad * 4, 256);
  unsigned short* nbf = (unsigned short*)p;
  p = align_up(p + (size_t)n_nodes * D * 2, 256);
  unsigned* binout = (unsigned*)p;
  p = align_up(p + (size_t)nblk_bin * CHUNK * 4, 256);
  unsigned short* dir = (unsigned short*)p;
  p = align_up(p + (size_t)nblk_bin * (nbuck + 1) * 2, 256);
  unsigned* sorted = (unsigned*)p;
  p = align_up(p + (size_t)nbuck * CAP * 4, 256);
  int* offsets = (int*)p;        p = align_up(p + (size_t)n_pad * 4, 256);
  int* ends    = (int*)p;        p = align_up(p + (size_t)n_pad * 4, 256);
  size_t needed = (size_t)(p - (char*)d_ws);

  const bool fits = (ws_size >= needed) && (n_nodes <= 65535) &&
                    (nbuck <= MAXBUCK) && (nblk_bin <= NCHUNK_MAX) &&
                    ((n_edges / (nbuck > 0 ? nbuck : 1)) * 3 < CAP);

  if (fits) {
    // stage 1: bin counting sort ∥ logit chain (one launch, co-resident)
    int nblk1 = (n_nodes + 63) / 64;
    logit_bin_kernel<<<nblk_bin + nblk1, 256, 0, stream>>>(
        Nm, W1, w2, explog, nbf, n_nodes, src, dst, binout, dir, n_edges,
        nbuck, nblk_bin);

    // stage 2: per-bucket merge
    merge_kernel<<<nbuck, 256, 0, stream>>>(binout, dir, sorted, offsets,
                                            ends, n_nodes, nbuck, nblk_bin);

    // stage 3: accumulation (wave per node pair, 16-edge-deep pipeline)
    int n_half = (n_nodes + 1) / 2;
    int ablk = (n_half + 3) / 4;  // 4 waves per block, each handles 2 nodes
    accum_sorted_kernel<<<ablk, 256, 0, stream>>>(
        offsets, ends, sorted, explog, nbf, out, n_nodes, n_half);
  } else {
    // fallback: scalar logit + R1 atomic path
    float* logit = explog;
    float* denom = denomF;
    hipMemsetAsync(logit, 0, (size_t)n_pad * sizeof(float), stream);
    hipMemsetAsync(denom, 0, (size_t)n_pad * sizeof(float), stream);
    hipMemsetAsync(out, 0, (size_t)out_size * sizeof(float), stream);
    int nblk1 = (n_nodes + NPB - 1) / NPB;
    logit_kernel<<<nblk1, 256, 0, stream>>>(Nm, W1, w2, logit, n_nodes);
    int eblk = (n_edges + 255) / 256;
    denom_kernel<<<eblk, 256, 0, stream>>>(src, dst, logit, denom, n_edges);
    int nblk3 = (n_edges + 3) / 4;
    scatter_kernel<<<nblk3, 256, 0, stream>>>(src, dst, logit, denom, Nm, out,
                                              n_edges);
  }
}